// Round 1
// baseline (1202.269 us; speedup 1.0000x reference)
//
#include <hip/hip_runtime.h>

#define N_NODES 50000
#define N_EDGES 400000
#define E_TOT   450000   // + self loops
#define NEG 0.2f

// ---------------- graph build ----------------

__global__ void zero_ints(int* p, int n){
    int i = blockIdx.x*256 + threadIdx.x;
    if(i < n) p[i] = 0;
}

__global__ void count_deg(const int* __restrict__ ei, int* __restrict__ deg){
    int e = blockIdx.x*256 + threadIdx.x;
    if(e >= E_TOT) return;
    int dst = (e < N_EDGES) ? ei[N_EDGES + e] : (e - N_EDGES);
    atomicAdd(&deg[dst], 1);
}

// single-block scan: reads deg from dw, writes exclusive prefix to rowptr AND dw (as write offsets)
__global__ void scan_deg(int* __restrict__ dw, int* __restrict__ rowptr){
    __shared__ int sh[1024];
    int carry = 0;
    for(int base = 0; base < N_NODES; base += 1024){
        int i = base + threadIdx.x;
        int v = (i < N_NODES) ? dw[i] : 0;
        sh[threadIdx.x] = v;
        __syncthreads();
        for(int off = 1; off < 1024; off <<= 1){
            int t = (threadIdx.x >= off) ? sh[threadIdx.x - off] : 0;
            __syncthreads();
            sh[threadIdx.x] += t;
            __syncthreads();
        }
        int excl = carry + sh[threadIdx.x] - v;
        if(i < N_NODES){ rowptr[i] = excl; dw[i] = excl; }
        carry += sh[1023];
        __syncthreads();
    }
    if(threadIdx.x == 0) rowptr[N_NODES] = carry;
}

__global__ void scatter_edges(const int* __restrict__ ei, int* __restrict__ wofs,
                              int* __restrict__ csr){
    int e = blockIdx.x*256 + threadIdx.x;
    if(e >= E_TOT) return;
    int src, dst;
    if(e < N_EDGES){ src = ei[e]; dst = ei[N_EDGES + e]; }
    else { src = dst = e - N_EDGES; }
    int pos = atomicAdd(&wofs[dst], 1);
    csr[pos] = src;
}

// ---------------- fp32 tiled GEMM: C[M,Nn] = A[M,K] @ B[K,Nn] ----------------
// 64x64 tile, BK=16, 256 threads, 4x4 micro-tile per thread.

template<int K>
__global__ __launch_bounds__(256) void gemm_tile(const float* __restrict__ A,
                                                 const float* __restrict__ B,
                                                 float* __restrict__ C,
                                                 int M, int Nn){
    __shared__ float As[16][68];   // [k][row], pad 68 keeps 16B alignment, <=2-way bank alias (free)
    __shared__ float Bs[16][64];   // [k][col]
    int tid = threadIdx.x;
    int tx = tid & 15, ty = tid >> 4;
    int brow = blockIdx.y * 64, bcol = blockIdx.x * 64;
    float acc[4][4] = {};
    int arow = tid >> 2, ac4 = tid & 3;   // A load: 1 float4 per thread
    int bk = tid >> 4, bc4 = tid & 15;    // B load: 1 float4 per thread

    for(int kt = 0; kt < K; kt += 16){
        float4 av = make_float4(0.f,0.f,0.f,0.f);
        int ar = brow + arow;
        if(ar < M) av = *(const float4*)&A[(long)ar*K + kt + ac4*4];
        As[ac4*4+0][arow] = av.x;
        As[ac4*4+1][arow] = av.y;
        As[ac4*4+2][arow] = av.z;
        As[ac4*4+3][arow] = av.w;
        float4 bv = *(const float4*)&B[(long)(kt+bk)*Nn + bcol + bc4*4];
        *(float4*)&Bs[bk][bc4*4] = bv;
        __syncthreads();
        #pragma unroll
        for(int kk = 0; kk < 16; kk++){
            float4 a4 = *(const float4*)&As[kk][ty*4];
            float4 b4 = *(const float4*)&Bs[kk][tx*4];
            float aa[4] = {a4.x, a4.y, a4.z, a4.w};
            float bb[4] = {b4.x, b4.y, b4.z, b4.w};
            #pragma unroll
            for(int i = 0; i < 4; i++)
                #pragma unroll
                for(int j = 0; j < 4; j++)
                    acc[i][j] += aa[i]*bb[j];
        }
        __syncthreads();
    }
    #pragma unroll
    for(int i = 0; i < 4; i++){
        int r = brow + ty*4 + i;
        if(r < M)
            *(float4*)&C[(long)r*Nn + bcol + tx*4] =
                make_float4(acc[i][0], acc[i][1], acc[i][2], acc[i][3]);
    }
}

// ---------------- node attention logits (H=8, C=64) ----------------
// al_s[n,h] = sum_c h[n,h,c]*a_s[h,c]; same for al_d. One thread per (n,h).

__global__ void node_logits(const float* __restrict__ h, const float* __restrict__ a_s,
                            const float* __restrict__ a_d,
                            float* __restrict__ als, float* __restrict__ ald){
    int t = blockIdx.x*256 + threadIdx.x;   // t = n*8 + hd
    if(t >= N_NODES*8) return;
    int hd = t & 7;
    const float* hp  = &h[(long)t * 64];    // == h[n*512 + hd*64]
    const float* asp = &a_s[hd*64];
    const float* adp = &a_d[hd*64];
    float s = 0.f, d = 0.f;
    #pragma unroll 8
    for(int c = 0; c < 64; c++){ float x = hp[c]; s += x*asp[c]; d += x*adp[c]; }
    als[t] = s; ald[t] = d;
}

// ---------------- edge softmax + aggregation (H=8, C=64), bias + ELU fused ----------------
// one wave per node; 4 waves (4 nodes) per block.

__global__ __launch_bounds__(256) void attn_agg(const float* __restrict__ h,
        const float* __restrict__ als, const float* __restrict__ ald,
        const int* __restrict__ rowptr, const int* __restrict__ csr,
        const float* __restrict__ bias, float* __restrict__ out){
    __shared__ float sm[4][8], sd[4][8];
    int wv = threadIdx.x >> 6, lane = threadIdx.x & 63;
    int n = blockIdx.x*4 + wv;            // grid = 12500 exactly, N divisible by 4
    int start = rowptr[n], end = rowptr[n+1];

    // phase A: per-head max & exp-sum. lane = e8*8 + hd
    int hd = lane & 7, e8 = lane >> 3;
    float aldv = ald[n*8 + hd];
    float lmax = -1e30f;
    for(int idx = start + e8; idx < end; idx += 8){
        int src = csr[idx];
        float v = als[src*8 + hd] + aldv;
        v = v > 0.f ? v : NEG*v;
        lmax = fmaxf(lmax, v);
    }
    for(int off = 8; off < 64; off <<= 1) lmax = fmaxf(lmax, __shfl_xor(lmax, off));
    float lsum = 0.f;
    for(int idx = start + e8; idx < end; idx += 8){
        int src = csr[idx];
        float v = als[src*8 + hd] + aldv;
        v = v > 0.f ? v : NEG*v;
        lsum += __expf(v - lmax);
    }
    for(int off = 8; off < 64; off <<= 1) lsum += __shfl_xor(lsum, off);
    if(lane < 8){ sm[wv][hd] = lmax; sd[wv][hd] = 1.f / lsum; }
    __syncthreads();

    // phase B: each lane owns 8 output channels: m = lane*8 + j, head = lane>>3
    int head = lane >> 3;
    float m = sm[wv][head], inv = sd[wv][head];
    float aldn = ald[n*8 + head];
    float acc[8] = {};
    for(int idx = start; idx < end; idx++){
        int src = csr[idx];
        float v = als[src*8 + head] + aldn;
        v = v > 0.f ? v : NEG*v;
        float alpha = __expf(v - m) * inv;
        const float4* hp = (const float4*)&h[(long)src*512 + lane*8];
        float4 h0 = hp[0], h1 = hp[1];
        acc[0] += alpha*h0.x; acc[1] += alpha*h0.y;
        acc[2] += alpha*h0.z; acc[3] += alpha*h0.w;
        acc[4] += alpha*h1.x; acc[5] += alpha*h1.y;
        acc[6] += alpha*h1.z; acc[7] += alpha*h1.w;
    }
    #pragma unroll
    for(int j = 0; j < 8; j++){
        float v = acc[j] + bias[lane*8 + j];
        out[(long)n*512 + lane*8 + j] = v > 0.f ? v : (__expf(v) - 1.f);  // ELU
    }
}

// ---------------- layer 2: GEMM [N,512]x[512,16] ----------------

__global__ __launch_bounds__(256) void gemm2_k(const float* __restrict__ A,
                                               const float* __restrict__ W,
                                               float* __restrict__ C){
    __shared__ float Ws[16][513];   // transposed, stride 513 -> conflict-free column reads
    for(int i = threadIdx.x; i < 512*16; i += 256){
        int k = i >> 4, c = i & 15;
        Ws[c][k] = W[i];
    }
    __syncthreads();
    int t = blockIdx.x*256 + threadIdx.x;   // t = row*16 + c, grid covers exactly
    int c = t & 15;
    long row = t >> 4;
    const float* ap = &A[row*512];
    const float* wp = &Ws[c][0];
    float acc = 0.f;
    #pragma unroll 4
    for(int k = 0; k < 512; k++) acc += ap[k]*wp[k];
    C[t] = acc;
}

__global__ void node_logits2(const float* __restrict__ h2, const float* __restrict__ a_s,
                             const float* __restrict__ a_d,
                             float* __restrict__ als, float* __restrict__ ald){
    int n = blockIdx.x*256 + threadIdx.x;
    if(n >= N_NODES) return;
    float s = 0.f, d = 0.f;
    #pragma unroll
    for(int c = 0; c < 16; c++){ float x = h2[n*16+c]; s += x*a_s[c]; d += x*a_d[c]; }
    als[n] = s; ald[n] = d;
}

// final aggregation: H=1, C=16, +b2, no ELU (mean over 1 head = identity)
__global__ __launch_bounds__(256) void attn_agg2(const float* __restrict__ h2,
        const float* __restrict__ als, const float* __restrict__ ald,
        const int* __restrict__ rowptr, const int* __restrict__ csr,
        const float* __restrict__ b2, float* __restrict__ out){
    int wv = threadIdx.x >> 6, lane = threadIdx.x & 63;
    int n = blockIdx.x*4 + wv;
    int start = rowptr[n], end = rowptr[n+1];
    float aldv = ald[n];
    float m = -1e30f;
    for(int idx = start; idx < end; idx++){
        float v = als[csr[idx]] + aldv; v = v > 0.f ? v : NEG*v;
        m = fmaxf(m, v);
    }
    float s = 0.f;
    for(int idx = start; idx < end; idx++){
        float v = als[csr[idx]] + aldv; v = v > 0.f ? v : NEG*v;
        s += __expf(v - m);
    }
    float inv = 1.f / s;
    if(lane < 16){
        float acc = 0.f;
        for(int idx = start; idx < end; idx++){
            int src = csr[idx];
            float v = als[src] + aldv; v = v > 0.f ? v : NEG*v;
            float alpha = __expf(v - m) * inv;
            acc += alpha * h2[src*16 + lane];
        }
        out[n*16 + lane] = acc + b2[lane];
    }
}

// ---------------- launch ----------------

extern "C" void kernel_launch(void* const* d_in, const int* in_sizes, int n_in,
                              void* d_out, int out_size, void* d_ws, size_t ws_size,
                              hipStream_t stream) {
    const float* x    = (const float*)d_in[0];
    const int*   ei   = (const int*)  d_in[1];
    const float* W0   = (const float*)d_in[2];
    const float* a_s0 = (const float*)d_in[3];
    const float* a_d0 = (const float*)d_in[4];
    const float* b0   = (const float*)d_in[5];
    const float* W1   = (const float*)d_in[6];
    const float* a_s1 = (const float*)d_in[7];
    const float* a_d1 = (const float*)d_in[8];
    const float* b1   = (const float*)d_in[9];
    const float* W2   = (const float*)d_in[10];
    const float* a_s2 = (const float*)d_in[11];
    const float* a_d2 = (const float*)d_in[12];
    const float* b2   = (const float*)d_in[13];
    float* out = (float*)d_out;

    char* w = (char*)d_ws;
    auto alloc = [&](size_t bytes){ void* p = (void*)w; w += (bytes + 255) & ~(size_t)255; return p; };
    int*   rowptr = (int*)  alloc((N_NODES+1)*sizeof(int));
    int*   wofs   = (int*)  alloc(N_NODES*sizeof(int));      // doubles as deg
    int*   csr    = (int*)  alloc(E_TOT*sizeof(int));
    float* als    = (float*)alloc((size_t)N_NODES*8*sizeof(float));
    float* ald    = (float*)alloc((size_t)N_NODES*8*sizeof(float));
    float* bufA   = (float*)alloc((size_t)N_NODES*512*sizeof(float));
    float* bufB   = (float*)alloc((size_t)N_NODES*512*sizeof(float));
    float* h2     = (float*)alloc((size_t)N_NODES*16*sizeof(float));

    // graph build (once per launch; reused for all 3 layers)
    zero_ints<<<(N_NODES+255)/256, 256, 0, stream>>>(wofs, N_NODES);
    count_deg<<<(E_TOT+255)/256, 256, 0, stream>>>(ei, wofs);
    scan_deg<<<1, 1024, 0, stream>>>(wofs, rowptr);
    scatter_edges<<<(E_TOT+255)/256, 256, 0, stream>>>(ei, wofs, csr);

    // layer 0: x[N,128] @ W0[128,512]
    gemm_tile<128><<<dim3(8, (N_NODES+63)/64), 256, 0, stream>>>(x, W0, bufA, N_NODES, 512);
    node_logits<<<(N_NODES*8+255)/256, 256, 0, stream>>>(bufA, a_s0, a_d0, als, ald);
    attn_agg<<<N_NODES/4, 256, 0, stream>>>(bufA, als, ald, rowptr, csr, b0, bufB);

    // layer 1: out0[N,512] @ W1[512,512]
    gemm_tile<512><<<dim3(8, (N_NODES+63)/64), 256, 0, stream>>>(bufB, W1, bufA, N_NODES, 512);
    node_logits<<<(N_NODES*8+255)/256, 256, 0, stream>>>(bufA, a_s1, a_d1, als, ald);
    attn_agg<<<N_NODES/4, 256, 0, stream>>>(bufA, als, ald, rowptr, csr, b1, bufB);

    // layer 2: out1[N,512] @ W2[512,16], H=1
    gemm2_k<<<(N_NODES*16)/256, 256, 0, stream>>>(bufB, W2, h2);
    node_logits2<<<(N_NODES+255)/256, 256, 0, stream>>>(h2, a_s2, a_d2, als, ald);
    attn_agg2<<<N_NODES/4, 256, 0, stream>>>(h2, als, ald, rowptr, csr, b2, out);
}

// Round 2
// 813.440 us; speedup vs baseline: 1.4780x; 1.4780x over previous
//
#include <hip/hip_runtime.h>

#define N_NODES 50000
#define N_EDGES 400000
#define E_TOT   450000   // + self loops
#define NEG 0.2f

typedef unsigned short ushort_t;
typedef __attribute__((ext_vector_type(8))) short  short8;   // 8 bf16 (4 VGPRs) MFMA A/B frag
typedef __attribute__((ext_vector_type(4))) float  f32x4;    // MFMA C/D frag
typedef __attribute__((ext_vector_type(8))) unsigned short ushort8;

__device__ __forceinline__ ushort_t f2bf(float f){
    union { float f; unsigned u; } v; v.f = f;
    unsigned u = v.u;
    return (ushort_t)((u + 0x7FFFu + ((u >> 16) & 1u)) >> 16);   // RNE
}
__device__ __forceinline__ float bflo(unsigned u){
    union { unsigned u; float f; } v; v.u = u << 16; return v.f;
}
__device__ __forceinline__ float bfhi(unsigned u){
    union { unsigned u; float f; } v; v.u = u & 0xFFFF0000u; return v.f;
}
__device__ __forceinline__ void gload_lds16(const void* g, void* l){
    __builtin_amdgcn_global_load_lds((const __attribute__((address_space(1))) void*)g,
                                     (__attribute__((address_space(3))) void*)l, 16, 0, 0);
}

// ---------------- graph build ----------------

__global__ void zero_ints(int* p, int n){
    int i = blockIdx.x*256 + threadIdx.x;
    if(i < n) p[i] = 0;
}

__global__ void count_deg(const int* __restrict__ ei, int* __restrict__ deg){
    int e = blockIdx.x*256 + threadIdx.x;
    if(e >= E_TOT) return;
    int dst = (e < N_EDGES) ? ei[N_EDGES + e] : (e - N_EDGES);
    atomicAdd(&deg[dst], 1);
}

__global__ void scan_deg(int* __restrict__ dw, int* __restrict__ rowptr){
    __shared__ int sh[1024];
    int carry = 0;
    for(int base = 0; base < N_NODES; base += 1024){
        int i = base + threadIdx.x;
        int v = (i < N_NODES) ? dw[i] : 0;
        sh[threadIdx.x] = v;
        __syncthreads();
        for(int off = 1; off < 1024; off <<= 1){
            int t = (threadIdx.x >= off) ? sh[threadIdx.x - off] : 0;
            __syncthreads();
            sh[threadIdx.x] += t;
            __syncthreads();
        }
        int excl = carry + sh[threadIdx.x] - v;
        if(i < N_NODES){ rowptr[i] = excl; dw[i] = excl; }
        carry += sh[1023];
        __syncthreads();
    }
    if(threadIdx.x == 0) rowptr[N_NODES] = carry;
}

__global__ void scatter_edges(const int* __restrict__ ei, int* __restrict__ wofs,
                              int* __restrict__ csr){
    int e = blockIdx.x*256 + threadIdx.x;
    if(e >= E_TOT) return;
    int src, dst;
    if(e < N_EDGES){ src = ei[e]; dst = ei[N_EDGES + e]; }
    else { src = dst = e - N_EDGES; }
    int pos = atomicAdd(&wofs[dst], 1);
    csr[pos] = src;
}

// ---------------- fp32 -> bf16 conversions ----------------

__global__ void cvt_bf16(const float* __restrict__ in, ushort_t* __restrict__ out, int n){
    int i = blockIdx.x*256 + threadIdx.x;
    if(i < n) out[i] = f2bf(in[i]);
}

// Wt[n*K + k] = bf16(W[k*N + n]) ; launched with K*N threads (output-coalesced)
__global__ void cvt_transpose_bf16(const float* __restrict__ W, ushort_t* __restrict__ Wt,
                                   int K, int N){
    int t = blockIdx.x*256 + threadIdx.x;
    if(t >= K*N) return;
    int n = t / K, k = t - n*K;
    Wt[t] = f2bf(W[(size_t)k*N + n]);
}

// ---------------- bf16 MFMA GEMM: C[M,512] = A[M,K] @ Bt[512,K]^T ----------------
// 128x128 tile, BK=32, 256 threads = 4 waves (2x2 of 64x64), mfma_f32_16x16x32_bf16.
// Staging via global_load_lds width 16 (wave-uniform base + lane*16 layout).

template<int K>
__global__ __launch_bounds__(256) void gemm_bt(const ushort_t* __restrict__ A,
                                               const ushort_t* __restrict__ Bt,
                                               float* __restrict__ C, int M){
    __shared__ ushort_t As[128*32];   // row-major [128][32] bf16, 8 KB
    __shared__ ushort_t Bs[128*32];   // rows are N-tile cols, K-contig
    int tid  = threadIdx.x;
    int wave = tid >> 6, lane = tid & 63;
    int wm = wave & 1, wn = wave >> 1;
    int row0 = blockIdx.y * 128;
    int col0 = blockIdx.x * 128;

    f32x4 acc[4][4] = {};

    int lrow = lane >> 2;          // 0..15 within a 16-row segment
    int lchk = (lane & 3) * 8;     // k-chunk offset (8 bf16 = 16 B)

    for(int kt = 0; kt < K; kt += 32){
        #pragma unroll
        for(int s = 0; s < 2; s++){
            int seg = wave*2 + s;                      // 0..7 -> rows seg*16..+15
            int ar = row0 + seg*16 + lrow;
            ar = ar < M ? ar : M-1;                    // clamp (stores guarded)
            gload_lds16(A  + (size_t)ar*K + kt + lchk, As + seg*512);
            int br = col0 + seg*16 + lrow;             // always valid (N=512)
            gload_lds16(Bt + (size_t)br*K + kt + lchk, Bs + seg*512);
        }
        __syncthreads();

        short8 a[4], b[4];
        int fm = lane & 15, fq = (lane >> 4) * 8;
        #pragma unroll
        for(int t = 0; t < 4; t++){
            a[t] = *(const short8*)&As[(wm*64 + t*16 + fm)*32 + fq];
            b[t] = *(const short8*)&Bs[(wn*64 + t*16 + fm)*32 + fq];
        }
        #pragma unroll
        for(int i = 0; i < 4; i++)
            #pragma unroll
            for(int j = 0; j < 4; j++)
                acc[i][j] = __builtin_amdgcn_mfma_f32_16x16x32_bf16(a[i], b[j], acc[i][j], 0, 0, 0);
        __syncthreads();
    }

    // C/D layout: col = lane&15, row = (lane>>4)*4 + reg
    int cm = (lane >> 4) * 4, cn = lane & 15;
    #pragma unroll
    for(int i = 0; i < 4; i++){
        #pragma unroll
        for(int p = 0; p < 4; p++){
            int r = row0 + wm*64 + i*16 + cm + p;
            if(r < M){
                float* cp = &C[(size_t)r*512 + col0 + wn*64 + cn];
                #pragma unroll
                for(int j = 0; j < 4; j++) cp[j*16] = acc[i][j][p];
            }
        }
    }
}

// ---------------- node attention logits (H=8, C=64) ----------------

__global__ void node_logits(const float* __restrict__ h, const float* __restrict__ a_s,
                            const float* __restrict__ a_d,
                            float* __restrict__ als, float* __restrict__ ald){
    int t = blockIdx.x*256 + threadIdx.x;   // t = n*8 + hd
    if(t >= N_NODES*8) return;
    int hd = t & 7;
    const float* hp  = &h[(long)t * 64];
    const float* asp = &a_s[hd*64];
    const float* adp = &a_d[hd*64];
    float s = 0.f, d = 0.f;
    #pragma unroll 8
    for(int c = 0; c < 64; c++){ float x = hp[c]; s += x*asp[c]; d += x*adp[c]; }
    als[t] = s; ald[t] = d;
}

// ---------------- edge softmax + aggregation, bias + ELU fused, bf16 output ----------------

__global__ __launch_bounds__(256) void attn_agg(const float* __restrict__ h,
        const float* __restrict__ als, const float* __restrict__ ald,
        const int* __restrict__ rowptr, const int* __restrict__ csr,
        const float* __restrict__ bias, ushort_t* __restrict__ out){
    __shared__ float sm[4][8], sd[4][8];
    int wv = threadIdx.x >> 6, lane = threadIdx.x & 63;
    int n = blockIdx.x*4 + wv;
    int start = rowptr[n], end = rowptr[n+1];

    int hd = lane & 7, e8 = lane >> 3;
    float aldv = ald[n*8 + hd];
    float lmax = -1e30f;
    for(int idx = start + e8; idx < end; idx += 8){
        int src = csr[idx];
        float v = als[src*8 + hd] + aldv;
        v = v > 0.f ? v : NEG*v;
        lmax = fmaxf(lmax, v);
    }
    for(int off = 8; off < 64; off <<= 1) lmax = fmaxf(lmax, __shfl_xor(lmax, off));
    float lsum = 0.f;
    for(int idx = start + e8; idx < end; idx += 8){
        int src = csr[idx];
        float v = als[src*8 + hd] + aldv;
        v = v > 0.f ? v : NEG*v;
        lsum += __expf(v - lmax);
    }
    for(int off = 8; off < 64; off <<= 1) lsum += __shfl_xor(lsum, off);
    if(lane < 8){ sm[wv][hd] = lmax; sd[wv][hd] = 1.f / lsum; }
    __syncthreads();

    int head = lane >> 3;
    float m = sm[wv][head], inv = sd[wv][head];
    float aldn = ald[n*8 + head];
    float acc[8] = {};
    for(int idx = start; idx < end; idx++){
        int src = csr[idx];
        float v = als[src*8 + head] + aldn;
        v = v > 0.f ? v : NEG*v;
        float alpha = __expf(v - m) * inv;
        const float4* hp = (const float4*)&h[(long)src*512 + lane*8];
        float4 h0 = hp[0], h1 = hp[1];
        acc[0] += alpha*h0.x; acc[1] += alpha*h0.y;
        acc[2] += alpha*h0.z; acc[3] += alpha*h0.w;
        acc[4] += alpha*h1.x; acc[5] += alpha*h1.y;
        acc[6] += alpha*h1.z; acc[7] += alpha*h1.w;
    }
    ushort8 o;
    #pragma unroll
    for(int j = 0; j < 8; j++){
        float v = acc[j] + bias[lane*8 + j];
        v = v > 0.f ? v : (__expf(v) - 1.f);   // ELU
        o[j] = f2bf(v);
    }
    *(ushort8*)&out[(size_t)n*512 + lane*8] = o;   // 16 B store
}

// ---------------- layer 2: GEMM [N,512](bf16) x [512,16](f32) ----------------

__global__ __launch_bounds__(256) void gemm2_k(const ushort_t* __restrict__ A,
                                               const float* __restrict__ W,
                                               float* __restrict__ C){
    __shared__ float Ws[16][513];
    for(int i = threadIdx.x; i < 512*16; i += 256){
        int k = i >> 4, c = i & 15;
        Ws[c][k] = W[i];
    }
    __syncthreads();
    int t = blockIdx.x*256 + threadIdx.x;
    int c = t & 15;
    long row = t >> 4;
    const ushort_t* ap = &A[row*512];
    const float* wp = &Ws[c][0];
    float acc = 0.f;
    for(int k = 0; k < 512; k += 8){
        uint4 p = *(const uint4*)&ap[k];   // 8 bf16
        acc += bflo(p.x)*wp[k+0] + bfhi(p.x)*wp[k+1]
             + bflo(p.y)*wp[k+2] + bfhi(p.y)*wp[k+3]
             + bflo(p.z)*wp[k+4] + bfhi(p.z)*wp[k+5]
             + bflo(p.w)*wp[k+6] + bfhi(p.w)*wp[k+7];
    }
    C[t] = acc;
}

__global__ void node_logits2(const float* __restrict__ h2, const float* __restrict__ a_s,
                             const float* __restrict__ a_d,
                             float* __restrict__ als, float* __restrict__ ald){
    int n = blockIdx.x*256 + threadIdx.x;
    if(n >= N_NODES) return;
    float s = 0.f, d = 0.f;
    #pragma unroll
    for(int c = 0; c < 16; c++){ float x = h2[n*16+c]; s += x*a_s[c]; d += x*a_d[c]; }
    als[n] = s; ald[n] = d;
}

__global__ __launch_bounds__(256) void attn_agg2(const float* __restrict__ h2,
        const float* __restrict__ als, const float* __restrict__ ald,
        const int* __restrict__ rowptr, const int* __restrict__ csr,
        const float* __restrict__ b2, float* __restrict__ out){
    int wv = threadIdx.x >> 6, lane = threadIdx.x & 63;
    int n = blockIdx.x*4 + wv;
    int start = rowptr[n], end = rowptr[n+1];
    float aldv = ald[n];
    float m = -1e30f;
    for(int idx = start; idx < end; idx++){
        float v = als[csr[idx]] + aldv; v = v > 0.f ? v : NEG*v;
        m = fmaxf(m, v);
    }
    float s = 0.f;
    for(int idx = start; idx < end; idx++){
        float v = als[csr[idx]] + aldv; v = v > 0.f ? v : NEG*v;
        s += __expf(v - m);
    }
    float inv = 1.f / s;
    if(lane < 16){
        float acc = 0.f;
        for(int idx = start; idx < end; idx++){
            int src = csr[idx];
            float v = als[src] + aldv; v = v > 0.f ? v : NEG*v;
            float alpha = __expf(v - m) * inv;
            acc += alpha * h2[src*16 + lane];
        }
        out[n*16 + lane] = acc + b2[lane];
    }
}

// ---------------- launch ----------------

extern "C" void kernel_launch(void* const* d_in, const int* in_sizes, int n_in,
                              void* d_out, int out_size, void* d_ws, size_t ws_size,
                              hipStream_t stream) {
    const float* x    = (const float*)d_in[0];
    const int*   ei   = (const int*)  d_in[1];
    const float* W0   = (const float*)d_in[2];
    const float* a_s0 = (const float*)d_in[3];
    const float* a_d0 = (const float*)d_in[4];
    const float* b0   = (const float*)d_in[5];
    const float* W1   = (const float*)d_in[6];
    const float* a_s1 = (const float*)d_in[7];
    const float* a_d1 = (const float*)d_in[8];
    const float* b1   = (const float*)d_in[9];
    const float* W2   = (const float*)d_in[10];
    const float* a_s2 = (const float*)d_in[11];
    const float* a_d2 = (const float*)d_in[12];
    const float* b2   = (const float*)d_in[13];
    float* out = (float*)d_out;

    char* w = (char*)d_ws;
    auto alloc = [&](size_t bytes){ void* p = (void*)w; w += (bytes + 255) & ~(size_t)255; return p; };
    int*      rowptr = (int*)     alloc((N_NODES+1)*sizeof(int));
    int*      wofs   = (int*)     alloc(N_NODES*sizeof(int));
    int*      csr    = (int*)     alloc(E_TOT*sizeof(int));
    float*    als    = (float*)   alloc((size_t)N_NODES*8*sizeof(float));
    float*    ald    = (float*)   alloc((size_t)N_NODES*8*sizeof(float));
    float*    bufA   = (float*)   alloc((size_t)N_NODES*512*sizeof(float));   // h (fp32 GEMM out)
    ushort_t* hbf    = (ushort_t*)alloc((size_t)N_NODES*512*sizeof(ushort_t));// bf16 GEMM A in
    ushort_t* xbf    = (ushort_t*)alloc((size_t)N_NODES*128*sizeof(ushort_t));
    ushort_t* W0t    = (ushort_t*)alloc((size_t)512*128*sizeof(ushort_t));
    ushort_t* W1t    = (ushort_t*)alloc((size_t)512*512*sizeof(ushort_t));
    float*    h2     = (float*)   alloc((size_t)N_NODES*16*sizeof(float));

    // graph build
    zero_ints<<<(N_NODES+255)/256, 256, 0, stream>>>(wofs, N_NODES);
    count_deg<<<(E_TOT+255)/256, 256, 0, stream>>>(ei, wofs);
    scan_deg<<<1, 1024, 0, stream>>>(wofs, rowptr);
    scatter_edges<<<(E_TOT+255)/256, 256, 0, stream>>>(ei, wofs, csr);

    // bf16 conversions
    cvt_bf16<<<(N_NODES*128+255)/256, 256, 0, stream>>>(x, xbf, N_NODES*128);
    cvt_transpose_bf16<<<(512*128+255)/256, 256, 0, stream>>>(W0, W0t, 128, 512);
    cvt_transpose_bf16<<<(512*512+255)/256, 256, 0, stream>>>(W1, W1t, 512, 512);

    // layer 0
    gemm_bt<128><<<dim3(4, (N_NODES+127)/128), 256, 0, stream>>>(xbf, W0t, bufA, N_NODES);
    node_logits<<<(N_NODES*8+255)/256, 256, 0, stream>>>(bufA, a_s0, a_d0, als, ald);
    attn_agg<<<N_NODES/4, 256, 0, stream>>>(bufA, als, ald, rowptr, csr, b0, hbf);

    // layer 1
    gemm_bt<512><<<dim3(4, (N_NODES+127)/128), 256, 0, stream>>>(hbf, W1t, bufA, N_NODES);
    node_logits<<<(N_NODES*8+255)/256, 256, 0, stream>>>(bufA, a_s1, a_d1, als, ald);
    attn_agg<<<N_NODES/4, 256, 0, stream>>>(bufA, als, ald, rowptr, csr, b1, hbf);

    // layer 2
    gemm2_k<<<(N_NODES*16)/256, 256, 0, stream>>>(hbf, W2, h2);
    node_logits2<<<(N_NODES+255)/256, 256, 0, stream>>>(h2, a_s2, a_d2, als, ald);
    attn_agg2<<<N_NODES/4, 256, 0, stream>>>(h2, als, ald, rowptr, csr, b2, out);
}

// Round 3
// 679.082 us; speedup vs baseline: 1.7704x; 1.1979x over previous
//
#include <hip/hip_runtime.h>

#define N_NODES 50000
#define N_EDGES 400000
#define E_TOT   450000   // + self loops
#define NEG 0.2f

typedef unsigned short ushort_t;
typedef __attribute__((ext_vector_type(8))) short  short8;   // 8 bf16 (4 VGPRs) MFMA A/B frag
typedef __attribute__((ext_vector_type(4))) float  f32x4;    // MFMA C/D frag
typedef __attribute__((ext_vector_type(8))) unsigned short ushort8;

__device__ __forceinline__ ushort_t f2bf(float f){
    union { float f; unsigned u; } v; v.f = f;
    unsigned u = v.u;
    return (ushort_t)((u + 0x7FFFu + ((u >> 16) & 1u)) >> 16);   // RNE
}
__device__ __forceinline__ float bflo(unsigned u){
    union { unsigned u; float f; } v; v.u = u << 16; return v.f;
}
__device__ __forceinline__ float bfhi(unsigned u){
    union { unsigned u; float f; } v; v.u = u & 0xFFFF0000u; return v.f;
}
__device__ __forceinline__ void gload_lds16(const void* g, void* l){
    __builtin_amdgcn_global_load_lds((const __attribute__((address_space(1))) void*)g,
                                     (__attribute__((address_space(3))) void*)l, 16, 0, 0);
}

// ---------------- graph build ----------------

__global__ void zero_ints(int* p, int n){
    int i = blockIdx.x*256 + threadIdx.x;
    if(i < n) p[i] = 0;
}

__global__ void count_deg(const int* __restrict__ ei, int* __restrict__ deg){
    int e = blockIdx.x*256 + threadIdx.x;
    if(e >= E_TOT) return;
    int dst = (e < N_EDGES) ? ei[N_EDGES + e] : (e - N_EDGES);
    atomicAdd(&deg[dst], 1);
}

__global__ void scan_deg(int* __restrict__ dw, int* __restrict__ rowptr){
    __shared__ int sh[1024];
    int carry = 0;
    for(int base = 0; base < N_NODES; base += 1024){
        int i = base + threadIdx.x;
        int v = (i < N_NODES) ? dw[i] : 0;
        sh[threadIdx.x] = v;
        __syncthreads();
        for(int off = 1; off < 1024; off <<= 1){
            int t = (threadIdx.x >= off) ? sh[threadIdx.x - off] : 0;
            __syncthreads();
            sh[threadIdx.x] += t;
            __syncthreads();
        }
        int excl = carry + sh[threadIdx.x] - v;
        if(i < N_NODES){ rowptr[i] = excl; dw[i] = excl; }
        carry += sh[1023];
        __syncthreads();
    }
    if(threadIdx.x == 0) rowptr[N_NODES] = carry;
}

__global__ void scatter_edges(const int* __restrict__ ei, int* __restrict__ wofs,
                              int* __restrict__ csr){
    int e = blockIdx.x*256 + threadIdx.x;
    if(e >= E_TOT) return;
    int src, dst;
    if(e < N_EDGES){ src = ei[e]; dst = ei[N_EDGES + e]; }
    else { src = dst = e - N_EDGES; }
    int pos = atomicAdd(&wofs[dst], 1);
    csr[pos] = src;
}

// ---------------- fp32 -> bf16 conversions ----------------

__global__ void cvt_bf16(const float* __restrict__ in, ushort_t* __restrict__ out, int n){
    int i = blockIdx.x*256 + threadIdx.x;
    if(i < n) out[i] = f2bf(in[i]);
}

// Wt[n*K + k] = bf16(W[k*N + n])
__global__ void cvt_transpose_bf16(const float* __restrict__ W, ushort_t* __restrict__ Wt,
                                   int K, int N){
    int t = blockIdx.x*256 + threadIdx.x;
    if(t >= K*N) return;
    int n = t / K, k = t - n*K;
    Wt[t] = f2bf(W[(size_t)k*N + n]);
}

// ---------------- bf16 MFMA GEMM: Cb[M,512](bf16) = A[M,K] @ Bt[512,K]^T ----------------
// 128x128 tile, BK=32, 4 waves (2x2 of 64x64), mfma_f32_16x16x32_bf16, bf16 epilogue.

template<int K>
__global__ __launch_bounds__(256) void gemm_bt(const ushort_t* __restrict__ A,
                                               const ushort_t* __restrict__ Bt,
                                               ushort_t* __restrict__ Cb, int M){
    __shared__ ushort_t As[128*32];
    __shared__ ushort_t Bs[128*32];
    int tid  = threadIdx.x;
    int wave = tid >> 6, lane = tid & 63;
    int wm = wave & 1, wn = wave >> 1;
    int row0 = blockIdx.y * 128;
    int col0 = blockIdx.x * 128;

    f32x4 acc[4][4] = {};

    int lrow = lane >> 2;
    int lchk = (lane & 3) * 8;

    for(int kt = 0; kt < K; kt += 32){
        #pragma unroll
        for(int s = 0; s < 2; s++){
            int seg = wave*2 + s;
            int ar = row0 + seg*16 + lrow;
            ar = ar < M ? ar : M-1;
            gload_lds16(A  + (size_t)ar*K + kt + lchk, As + seg*512);
            int br = col0 + seg*16 + lrow;
            gload_lds16(Bt + (size_t)br*K + kt + lchk, Bs + seg*512);
        }
        __syncthreads();

        short8 a[4], b[4];
        int fm = lane & 15, fq = (lane >> 4) * 8;
        #pragma unroll
        for(int t = 0; t < 4; t++){
            a[t] = *(const short8*)&As[(wm*64 + t*16 + fm)*32 + fq];
            b[t] = *(const short8*)&Bs[(wn*64 + t*16 + fm)*32 + fq];
        }
        #pragma unroll
        for(int i = 0; i < 4; i++)
            #pragma unroll
            for(int j = 0; j < 4; j++)
                acc[i][j] = __builtin_amdgcn_mfma_f32_16x16x32_bf16(a[i], b[j], acc[i][j], 0, 0, 0);
        __syncthreads();
    }

    // C/D layout: col = lane&15, row = (lane>>4)*4 + reg
    int cm = (lane >> 4) * 4, cn = lane & 15;
    #pragma unroll
    for(int i = 0; i < 4; i++){
        #pragma unroll
        for(int p = 0; p < 4; p++){
            int r = row0 + wm*64 + i*16 + cm + p;
            if(r < M){
                ushort_t* cp = &Cb[(size_t)r*512 + col0 + wn*64 + cn];
                #pragma unroll
                for(int j = 0; j < 4; j++) cp[j*16] = f2bf(acc[i][j][p]);
            }
        }
    }
}

// ---------------- node attention logits (H=8, C=64), bf16 h ----------------

__global__ void node_logits(const ushort_t* __restrict__ h, const float* __restrict__ a_s,
                            const float* __restrict__ a_d,
                            float* __restrict__ als, float* __restrict__ ald){
    int t = blockIdx.x*256 + threadIdx.x;   // t = n*8 + hd
    if(t >= N_NODES*8) return;
    int hd = t & 7;
    const ushort_t* hp = &h[(size_t)t * 64];
    const float* asp = &a_s[hd*64];
    const float* adp = &a_d[hd*64];
    float s = 0.f, d = 0.f;
    #pragma unroll
    for(int c = 0; c < 64; c += 8){
        uint4 p = *(const uint4*)&hp[c];
        float x0 = bflo(p.x), x1 = bfhi(p.x), x2 = bflo(p.y), x3 = bfhi(p.y);
        float x4 = bflo(p.z), x5 = bfhi(p.z), x6 = bflo(p.w), x7 = bfhi(p.w);
        s += x0*asp[c+0] + x1*asp[c+1] + x2*asp[c+2] + x3*asp[c+3]
           + x4*asp[c+4] + x5*asp[c+5] + x6*asp[c+6] + x7*asp[c+7];
        d += x0*adp[c+0] + x1*adp[c+1] + x2*adp[c+2] + x3*adp[c+3]
           + x4*adp[c+4] + x5*adp[c+5] + x6*adp[c+6] + x7*adp[c+7];
    }
    als[t] = s; ald[t] = d;
}

// ---------------- edge softmax + aggregation (bf16 h gather), bias + ELU, bf16 out ----------------

__global__ __launch_bounds__(256) void attn_agg(const ushort_t* __restrict__ h,
        const float* __restrict__ als, const float* __restrict__ ald,
        const int* __restrict__ rowptr, const int* __restrict__ csr,
        const float* __restrict__ bias, ushort_t* __restrict__ out){
    __shared__ float sm[4][8], sd[4][8];
    int wv = threadIdx.x >> 6, lane = threadIdx.x & 63;
    int n = blockIdx.x*4 + wv;
    int start = rowptr[n], end = rowptr[n+1];

    int hd = lane & 7, e8 = lane >> 3;
    float aldv = ald[n*8 + hd];
    float lmax = -1e30f;
    for(int idx = start + e8; idx < end; idx += 8){
        int src = csr[idx];
        float v = als[src*8 + hd] + aldv;
        v = v > 0.f ? v : NEG*v;
        lmax = fmaxf(lmax, v);
    }
    for(int off = 8; off < 64; off <<= 1) lmax = fmaxf(lmax, __shfl_xor(lmax, off));
    float lsum = 0.f;
    for(int idx = start + e8; idx < end; idx += 8){
        int src = csr[idx];
        float v = als[src*8 + hd] + aldv;
        v = v > 0.f ? v : NEG*v;
        lsum += __expf(v - lmax);
    }
    for(int off = 8; off < 64; off <<= 1) lsum += __shfl_xor(lsum, off);
    if(lane < 8){ sm[wv][hd] = lmax; sd[wv][hd] = 1.f / lsum; }
    __syncthreads();

    int head = lane >> 3;
    float m = sm[wv][head], inv = sd[wv][head];
    float aldn = ald[n*8 + head];
    float acc[8] = {};
    for(int idx = start; idx < end; idx++){
        int src = csr[idx];
        float v = als[src*8 + head] + aldn;
        v = v > 0.f ? v : NEG*v;
        float alpha = __expf(v - m) * inv;
        uint4 p = *(const uint4*)&h[(size_t)src*512 + lane*8];   // 8 bf16, 16 B
        acc[0] += alpha*bflo(p.x); acc[1] += alpha*bfhi(p.x);
        acc[2] += alpha*bflo(p.y); acc[3] += alpha*bfhi(p.y);
        acc[4] += alpha*bflo(p.z); acc[5] += alpha*bfhi(p.z);
        acc[6] += alpha*bflo(p.w); acc[7] += alpha*bfhi(p.w);
    }
    ushort8 o;
    #pragma unroll
    for(int j = 0; j < 8; j++){
        float v = acc[j] + bias[lane*8 + j];
        v = v > 0.f ? v : (__expf(v) - 1.f);   // ELU
        o[j] = f2bf(v);
    }
    *(ushort8*)&out[(size_t)n*512 + lane*8] = o;
}

// ---------------- layer 2: GEMM [N,512](bf16) x [512,16](f32) ----------------

__global__ __launch_bounds__(256) void gemm2_k(const ushort_t* __restrict__ A,
                                               const float* __restrict__ W,
                                               float* __restrict__ C){
    __shared__ float Ws[16][513];
    for(int i = threadIdx.x; i < 512*16; i += 256){
        int k = i >> 4, c = i & 15;
        Ws[c][k] = W[i];
    }
    __syncthreads();
    int t = blockIdx.x*256 + threadIdx.x;
    int c = t & 15;
    long row = t >> 4;
    const ushort_t* ap = &A[row*512];
    const float* wp = &Ws[c][0];
    float acc = 0.f;
    for(int k = 0; k < 512; k += 8){
        uint4 p = *(const uint4*)&ap[k];
        acc += bflo(p.x)*wp[k+0] + bfhi(p.x)*wp[k+1]
             + bflo(p.y)*wp[k+2] + bfhi(p.y)*wp[k+3]
             + bflo(p.z)*wp[k+4] + bfhi(p.z)*wp[k+5]
             + bflo(p.w)*wp[k+6] + bfhi(p.w)*wp[k+7];
    }
    C[t] = acc;
}

__global__ void node_logits2(const float* __restrict__ h2, const float* __restrict__ a_s,
                             const float* __restrict__ a_d,
                             float* __restrict__ als, float* __restrict__ ald){
    int n = blockIdx.x*256 + threadIdx.x;
    if(n >= N_NODES) return;
    float s = 0.f, d = 0.f;
    #pragma unroll
    for(int c = 0; c < 16; c++){ float x = h2[n*16+c]; s += x*a_s[c]; d += x*a_d[c]; }
    als[n] = s; ald[n] = d;
}

__global__ __launch_bounds__(256) void attn_agg2(const float* __restrict__ h2,
        const float* __restrict__ als, const float* __restrict__ ald,
        const int* __restrict__ rowptr, const int* __restrict__ csr,
        const float* __restrict__ b2, float* __restrict__ out){
    int wv = threadIdx.x >> 6, lane = threadIdx.x & 63;
    int n = blockIdx.x*4 + wv;
    int start = rowptr[n], end = rowptr[n+1];
    float aldv = ald[n];
    float m = -1e30f;
    for(int idx = start; idx < end; idx++){
        float v = als[csr[idx]] + aldv; v = v > 0.f ? v : NEG*v;
        m = fmaxf(m, v);
    }
    float s = 0.f;
    for(int idx = start; idx < end; idx++){
        float v = als[csr[idx]] + aldv; v = v > 0.f ? v : NEG*v;
        s += __expf(v - m);
    }
    float inv = 1.f / s;
    if(lane < 16){
        float acc = 0.f;
        for(int idx = start; idx < end; idx++){
            int src = csr[idx];
            float v = als[src] + aldv; v = v > 0.f ? v : NEG*v;
            float alpha = __expf(v - m) * inv;
            acc += alpha * h2[src*16 + lane];
        }
        out[n*16 + lane] = acc + b2[lane];
    }
}

// ---------------- launch ----------------

extern "C" void kernel_launch(void* const* d_in, const int* in_sizes, int n_in,
                              void* d_out, int out_size, void* d_ws, size_t ws_size,
                              hipStream_t stream) {
    const float* x    = (const float*)d_in[0];
    const int*   ei   = (const int*)  d_in[1];
    const float* W0   = (const float*)d_in[2];
    const float* a_s0 = (const float*)d_in[3];
    const float* a_d0 = (const float*)d_in[4];
    const float* b0   = (const float*)d_in[5];
    const float* W1   = (const float*)d_in[6];
    const float* a_s1 = (const float*)d_in[7];
    const float* a_d1 = (const float*)d_in[8];
    const float* b1   = (const float*)d_in[9];
    const float* W2   = (const float*)d_in[10];
    const float* a_s2 = (const float*)d_in[11];
    const float* a_d2 = (const float*)d_in[12];
    const float* b2   = (const float*)d_in[13];
    float* out = (float*)d_out;

    char* w = (char*)d_ws;
    auto alloc = [&](size_t bytes){ void* p = (void*)w; w += (bytes + 255) & ~(size_t)255; return p; };
    int*      rowptr = (int*)     alloc((N_NODES+1)*sizeof(int));
    int*      wofs   = (int*)     alloc(N_NODES*sizeof(int));
    int*      csr    = (int*)     alloc(E_TOT*sizeof(int));
    float*    als    = (float*)   alloc((size_t)N_NODES*8*sizeof(float));
    float*    ald    = (float*)   alloc((size_t)N_NODES*8*sizeof(float));
    ushort_t* hb     = (ushort_t*)alloc((size_t)N_NODES*512*sizeof(ushort_t)); // GEMM out (bf16)
    ushort_t* hbf    = (ushort_t*)alloc((size_t)N_NODES*512*sizeof(ushort_t)); // attn out (bf16)
    ushort_t* xbf    = (ushort_t*)alloc((size_t)N_NODES*128*sizeof(ushort_t));
    ushort_t* W0t    = (ushort_t*)alloc((size_t)512*128*sizeof(ushort_t));
    ushort_t* W1t    = (ushort_t*)alloc((size_t)512*512*sizeof(ushort_t));
    float*    h2     = (float*)   alloc((size_t)N_NODES*16*sizeof(float));

    // graph build
    zero_ints<<<(N_NODES+255)/256, 256, 0, stream>>>(wofs, N_NODES);
    count_deg<<<(E_TOT+255)/256, 256, 0, stream>>>(ei, wofs);
    scan_deg<<<1, 1024, 0, stream>>>(wofs, rowptr);
    scatter_edges<<<(E_TOT+255)/256, 256, 0, stream>>>(ei, wofs, csr);

    // bf16 conversions
    cvt_bf16<<<(N_NODES*128+255)/256, 256, 0, stream>>>(x, xbf, N_NODES*128);
    cvt_transpose_bf16<<<(512*128+255)/256, 256, 0, stream>>>(W0, W0t, 128, 512);
    cvt_transpose_bf16<<<(512*512+255)/256, 256, 0, stream>>>(W1, W1t, 512, 512);

    // layer 0
    gemm_bt<128><<<dim3(4, (N_NODES+127)/128), 256, 0, stream>>>(xbf, W0t, hb, N_NODES);
    node_logits<<<(N_NODES*8+255)/256, 256, 0, stream>>>(hb, a_s0, a_d0, als, ald);
    attn_agg<<<N_NODES/4, 256, 0, stream>>>(hb, als, ald, rowptr, csr, b0, hbf);

    // layer 1
    gemm_bt<512><<<dim3(4, (N_NODES+127)/128), 256, 0, stream>>>(hbf, W1t, hb, N_NODES);
    node_logits<<<(N_NODES*8+255)/256, 256, 0, stream>>>(hb, a_s1, a_d1, als, ald);
    attn_agg<<<N_NODES/4, 256, 0, stream>>>(hb, als, ald, rowptr, csr, b1, hbf);

    // layer 2
    gemm2_k<<<(N_NODES*16)/256, 256, 0, stream>>>(hbf, W2, h2);
    node_logits2<<<(N_NODES+255)/256, 256, 0, stream>>>(h2, a_s2, a_d2, als, ald);
    attn_agg2<<<N_NODES/4, 256, 0, stream>>>(h2, als, ald, rowptr, csr, b2, out);
}

// Round 4
// 647.068 us; speedup vs baseline: 1.8580x; 1.0495x over previous
//
#include <hip/hip_runtime.h>

#define N_NODES 50000
#define N_EDGES 400000
#define E_TOT   450000   // + self loops
#define NEG 0.2f

typedef unsigned short ushort_t;
typedef __attribute__((ext_vector_type(8))) short  short8;   // 8 bf16 (4 VGPRs) MFMA A/B frag
typedef __attribute__((ext_vector_type(4))) float  f32x4;    // MFMA C/D frag
typedef __attribute__((ext_vector_type(8))) unsigned short ushort8;

__device__ __forceinline__ ushort_t f2bf(float f){
    union { float f; unsigned u; } v; v.f = f;
    unsigned u = v.u;
    return (ushort_t)((u + 0x7FFFu + ((u >> 16) & 1u)) >> 16);   // RNE
}
__device__ __forceinline__ float bflo(unsigned u){
    union { unsigned u; float f; } v; v.u = u << 16; return v.f;
}
__device__ __forceinline__ float bfhi(unsigned u){
    union { unsigned u; float f; } v; v.u = u & 0xFFFF0000u; return v.f;
}
__device__ __forceinline__ void gload_lds16(const void* g, void* l){
    __builtin_amdgcn_global_load_lds((const __attribute__((address_space(1))) void*)g,
                                     (__attribute__((address_space(3))) void*)l, 16, 0, 0);
}

// ---------------- graph build ----------------

__global__ void zero_ints(int* p, int n){
    int i = blockIdx.x*256 + threadIdx.x;
    if(i < n) p[i] = 0;
}

__global__ void count_deg(const int* __restrict__ ei, int* __restrict__ deg){
    int e = blockIdx.x*256 + threadIdx.x;
    if(e >= E_TOT) return;
    int dst = (e < N_EDGES) ? ei[N_EDGES + e] : (e - N_EDGES);
    atomicAdd(&deg[dst], 1);
}

// single block, 1024 threads: thread t serially owns elements [t*49, t*49+49)
#define SCAN_CHUNK 49
__global__ void scan_deg(int* __restrict__ dw, int* __restrict__ rowptr){
    __shared__ int sh[1024];
    int t0 = threadIdx.x * SCAN_CHUNK;
    int sum = 0;
    for(int i = 0; i < SCAN_CHUNK; i++){
        int idx = t0 + i;
        if(idx < N_NODES) sum += dw[idx];
    }
    sh[threadIdx.x] = sum;
    __syncthreads();
    for(int off = 1; off < 1024; off <<= 1){
        int t = (threadIdx.x >= off) ? sh[threadIdx.x - off] : 0;
        __syncthreads();
        sh[threadIdx.x] += t;
        __syncthreads();
    }
    int run = sh[threadIdx.x] - sum;   // exclusive prefix of this thread's chunk
    for(int i = 0; i < SCAN_CHUNK; i++){
        int idx = t0 + i;
        if(idx < N_NODES){
            int v = dw[idx];
            rowptr[idx] = run;
            dw[idx] = run;
            run += v;
        }
    }
    if(threadIdx.x == 1023) rowptr[N_NODES] = run;
}

__global__ void scatter_edges(const int* __restrict__ ei, int* __restrict__ wofs,
                              int* __restrict__ csr){
    int e = blockIdx.x*256 + threadIdx.x;
    if(e >= E_TOT) return;
    int src, dst;
    if(e < N_EDGES){ src = ei[e]; dst = ei[N_EDGES + e]; }
    else { src = dst = e - N_EDGES; }
    int pos = atomicAdd(&wofs[dst], 1);
    csr[pos] = src;
}

// ---------------- fp32 -> bf16 conversions ----------------

__global__ void cvt_bf16(const float* __restrict__ in, ushort_t* __restrict__ out, int n){
    int i = blockIdx.x*256 + threadIdx.x;
    if(i < n) out[i] = f2bf(in[i]);
}

// Wt[n*K + k] = bf16(W[k*N + n])
__global__ void cvt_transpose_bf16(const float* __restrict__ W, ushort_t* __restrict__ Wt,
                                   int K, int N){
    int t = blockIdx.x*256 + threadIdx.x;
    if(t >= K*N) return;
    int n = t / K, k = t - n*K;
    Wt[t] = f2bf(W[(size_t)k*N + n]);
}

// ---------------- bf16 MFMA GEMM: Cb[M,512](bf16) = A[M,K] @ Bt[512,K]^T ----------------

template<int K>
__global__ __launch_bounds__(256) void gemm_bt(const ushort_t* __restrict__ A,
                                               const ushort_t* __restrict__ Bt,
                                               ushort_t* __restrict__ Cb, int M){
    __shared__ ushort_t As[128*32];
    __shared__ ushort_t Bs[128*32];
    int tid  = threadIdx.x;
    int wave = tid >> 6, lane = tid & 63;
    int wm = wave & 1, wn = wave >> 1;
    int row0 = blockIdx.y * 128;
    int col0 = blockIdx.x * 128;

    f32x4 acc[4][4] = {};

    int lrow = lane >> 2;
    int lchk = (lane & 3) * 8;

    for(int kt = 0; kt < K; kt += 32){
        #pragma unroll
        for(int s = 0; s < 2; s++){
            int seg = wave*2 + s;
            int ar = row0 + seg*16 + lrow;
            ar = ar < M ? ar : M-1;
            gload_lds16(A  + (size_t)ar*K + kt + lchk, As + seg*512);
            int br = col0 + seg*16 + lrow;
            gload_lds16(Bt + (size_t)br*K + kt + lchk, Bs + seg*512);
        }
        __syncthreads();

        short8 a[4], b[4];
        int fm = lane & 15, fq = (lane >> 4) * 8;
        #pragma unroll
        for(int t = 0; t < 4; t++){
            a[t] = *(const short8*)&As[(wm*64 + t*16 + fm)*32 + fq];
            b[t] = *(const short8*)&Bs[(wn*64 + t*16 + fm)*32 + fq];
        }
        #pragma unroll
        for(int i = 0; i < 4; i++)
            #pragma unroll
            for(int j = 0; j < 4; j++)
                acc[i][j] = __builtin_amdgcn_mfma_f32_16x16x32_bf16(a[i], b[j], acc[i][j], 0, 0, 0);
        __syncthreads();
    }

    int cm = (lane >> 4) * 4, cn = lane & 15;
    #pragma unroll
    for(int i = 0; i < 4; i++){
        #pragma unroll
        for(int p = 0; p < 4; p++){
            int r = row0 + wm*64 + i*16 + cm + p;
            if(r < M){
                ushort_t* cp = &Cb[(size_t)r*512 + col0 + wn*64 + cn];
                #pragma unroll
                for(int j = 0; j < 4; j++) cp[j*16] = f2bf(acc[i][j][p]);
            }
        }
    }
}

// ---------------- node attention logits (H=8, C=64), bf16 h ----------------

__global__ void node_logits(const ushort_t* __restrict__ h, const float* __restrict__ a_s,
                            const float* __restrict__ a_d,
                            float* __restrict__ als, float* __restrict__ ald){
    int t = blockIdx.x*256 + threadIdx.x;   // t = n*8 + hd
    if(t >= N_NODES*8) return;
    int hd = t & 7;
    const ushort_t* hp = &h[(size_t)t * 64];
    const float* asp = &a_s[hd*64];
    const float* adp = &a_d[hd*64];
    float s = 0.f, d = 0.f;
    #pragma unroll
    for(int c = 0; c < 64; c += 8){
        uint4 p = *(const uint4*)&hp[c];
        float x0 = bflo(p.x), x1 = bfhi(p.x), x2 = bflo(p.y), x3 = bfhi(p.y);
        float x4 = bflo(p.z), x5 = bfhi(p.z), x6 = bflo(p.w), x7 = bfhi(p.w);
        s += x0*asp[c+0] + x1*asp[c+1] + x2*asp[c+2] + x3*asp[c+3]
           + x4*asp[c+4] + x5*asp[c+5] + x6*asp[c+6] + x7*asp[c+7];
        d += x0*adp[c+0] + x1*adp[c+1] + x2*adp[c+2] + x3*adp[c+3]
           + x4*adp[c+4] + x5*adp[c+5] + x6*adp[c+6] + x7*adp[c+7];
    }
    als[t] = s; ald[t] = d;
}

// ---------------- edge softmax + aggregation (bf16 h gather), bias + ELU, bf16 out ----------------
// one wave per node; phase B depth-2 software pipeline for MLP.

__global__ __launch_bounds__(256) void attn_agg(const ushort_t* __restrict__ h,
        const float* __restrict__ als, const float* __restrict__ ald,
        const int* __restrict__ rowptr, const int* __restrict__ csr,
        const float* __restrict__ bias, ushort_t* __restrict__ out){
    __shared__ float sm[4][8], sd[4][8];
    int wv = threadIdx.x >> 6, lane = threadIdx.x & 63;
    int n = blockIdx.x*4 + wv;
    int start = rowptr[n], end = rowptr[n+1];

    int hd = lane & 7, e8 = lane >> 3;
    float aldv = ald[n*8 + hd];
    float lmax = -1e30f;
    for(int idx = start + e8; idx < end; idx += 8){
        int src = csr[idx];
        float v = als[src*8 + hd] + aldv;
        v = v > 0.f ? v : NEG*v;
        lmax = fmaxf(lmax, v);
    }
    for(int off = 8; off < 64; off <<= 1) lmax = fmaxf(lmax, __shfl_xor(lmax, off));
    float lsum = 0.f;
    for(int idx = start + e8; idx < end; idx += 8){
        int src = csr[idx];
        float v = als[src*8 + hd] + aldv;
        v = v > 0.f ? v : NEG*v;
        lsum += __expf(v - lmax);
    }
    for(int off = 8; off < 64; off <<= 1) lsum += __shfl_xor(lsum, off);
    if(lane < 8){ sm[wv][hd] = lmax; sd[wv][hd] = 1.f / lsum; }
    __syncthreads();

    int head = lane >> 3;
    float m = sm[wv][head], inv = sd[wv][head];
    float aldn = ald[n*8 + head];
    float acc[8] = {};

    // depth-2 pipeline: prefetch edge idx+1 while accumulating edge idx
    int idx = start;
    int src = csr[idx];
    uint4 p = *(const uint4*)&h[(size_t)src*512 + lane*8];
    float av = als[src*8 + head];
    while(true){
        int nidx = idx + 1;
        bool more = nidx < end;
        int nsrc = 0; uint4 np; float nav = 0.f;
        if(more){
            nsrc = csr[nidx];
            np = *(const uint4*)&h[(size_t)nsrc*512 + lane*8];
            nav = als[nsrc*8 + head];
        }
        float v = av + aldn; v = v > 0.f ? v : NEG*v;
        float alpha = __expf(v - m) * inv;
        acc[0] += alpha*bflo(p.x); acc[1] += alpha*bfhi(p.x);
        acc[2] += alpha*bflo(p.y); acc[3] += alpha*bfhi(p.y);
        acc[4] += alpha*bflo(p.z); acc[5] += alpha*bfhi(p.z);
        acc[6] += alpha*bflo(p.w); acc[7] += alpha*bfhi(p.w);
        if(!more) break;
        idx = nidx; p = np; av = nav;
    }

    ushort8 o;
    #pragma unroll
    for(int j = 0; j < 8; j++){
        float v = acc[j] + bias[lane*8 + j];
        v = v > 0.f ? v : (__expf(v) - 1.f);   // ELU
        o[j] = f2bf(v);
    }
    *(ushort8*)&out[(size_t)n*512 + lane*8] = o;
}

// ---------------- layer 2: GEMM [N,512](bf16) x [512,16](f32) ----------------

__global__ __launch_bounds__(256) void gemm2_k(const ushort_t* __restrict__ A,
                                               const float* __restrict__ W,
                                               float* __restrict__ C){
    __shared__ float Ws[16][513];
    for(int i = threadIdx.x; i < 512*16; i += 256){
        int k = i >> 4, c = i & 15;
        Ws[c][k] = W[i];
    }
    __syncthreads();
    int t = blockIdx.x*256 + threadIdx.x;
    int c = t & 15;
    long row = t >> 4;
    const ushort_t* ap = &A[row*512];
    const float* wp = &Ws[c][0];
    float acc = 0.f;
    for(int k = 0; k < 512; k += 8){
        uint4 p = *(const uint4*)&ap[k];
        acc += bflo(p.x)*wp[k+0] + bfhi(p.x)*wp[k+1]
             + bflo(p.y)*wp[k+2] + bfhi(p.y)*wp[k+3]
             + bflo(p.z)*wp[k+4] + bfhi(p.z)*wp[k+5]
             + bflo(p.w)*wp[k+6] + bfhi(p.w)*wp[k+7];
    }
    C[t] = acc;
}

__global__ void node_logits2(const float* __restrict__ h2, const float* __restrict__ a_s,
                             const float* __restrict__ a_d,
                             float* __restrict__ als, float* __restrict__ ald){
    int n = blockIdx.x*256 + threadIdx.x;
    if(n >= N_NODES) return;
    float s = 0.f, d = 0.f;
    #pragma unroll
    for(int c = 0; c < 16; c++){ float x = h2[n*16+c]; s += x*a_s[c]; d += x*a_d[c]; }
    als[n] = s; ald[n] = d;
}

// final layer agg: 16 lanes per node, 4 nodes per wave, 16 nodes per block
__global__ __launch_bounds__(256) void attn_agg2(const float* __restrict__ h2,
        const float* __restrict__ als, const float* __restrict__ ald,
        const int* __restrict__ rowptr, const int* __restrict__ csr,
        const float* __restrict__ b2, float* __restrict__ out){
    int wv = threadIdx.x >> 6, lane = threadIdx.x & 63;
    int q = lane >> 4, c = lane & 15;
    int n = blockIdx.x*16 + wv*4 + q;
    int start = rowptr[n], end = rowptr[n+1];
    float aldv = ald[n];

    // phase A: edges strided over the 16 lanes of this node's group
    float lmax = -1e30f;
    for(int idx = start + c; idx < end; idx += 16){
        float v = als[csr[idx]] + aldv; v = v > 0.f ? v : NEG*v;
        lmax = fmaxf(lmax, v);
    }
    #pragma unroll
    for(int off = 1; off < 16; off <<= 1) lmax = fmaxf(lmax, __shfl_xor(lmax, off));
    float lsum = 0.f;
    for(int idx = start + c; idx < end; idx += 16){
        float v = als[csr[idx]] + aldv; v = v > 0.f ? v : NEG*v;
        lsum += __expf(v - lmax);
    }
    #pragma unroll
    for(int off = 1; off < 16; off <<= 1) lsum += __shfl_xor(lsum, off);
    float inv = 1.f / lsum;

    // phase B: lane c accumulates channel c
    float acc = 0.f;
    for(int idx = start; idx < end; idx++){
        int src = csr[idx];
        float v = als[src] + aldv; v = v > 0.f ? v : NEG*v;
        float alpha = __expf(v - lmax) * inv;
        acc += alpha * h2[src*16 + c];
    }
    out[n*16 + c] = acc + b2[c];
}

// ---------------- launch ----------------

extern "C" void kernel_launch(void* const* d_in, const int* in_sizes, int n_in,
                              void* d_out, int out_size, void* d_ws, size_t ws_size,
                              hipStream_t stream) {
    const float* x    = (const float*)d_in[0];
    const int*   ei   = (const int*)  d_in[1];
    const float* W0   = (const float*)d_in[2];
    const float* a_s0 = (const float*)d_in[3];
    const float* a_d0 = (const float*)d_in[4];
    const float* b0   = (const float*)d_in[5];
    const float* W1   = (const float*)d_in[6];
    const float* a_s1 = (const float*)d_in[7];
    const float* a_d1 = (const float*)d_in[8];
    const float* b1   = (const float*)d_in[9];
    const float* W2   = (const float*)d_in[10];
    const float* a_s2 = (const float*)d_in[11];
    const float* a_d2 = (const float*)d_in[12];
    const float* b2   = (const float*)d_in[13];
    float* out = (float*)d_out;

    char* w = (char*)d_ws;
    auto alloc = [&](size_t bytes){ void* p = (void*)w; w += (bytes + 255) & ~(size_t)255; return p; };
    int*      rowptr = (int*)     alloc((N_NODES+1)*sizeof(int));
    int*      wofs   = (int*)     alloc(N_NODES*sizeof(int));
    int*      csr    = (int*)     alloc(E_TOT*sizeof(int));
    float*    als    = (float*)   alloc((size_t)N_NODES*8*sizeof(float));
    float*    ald    = (float*)   alloc((size_t)N_NODES*8*sizeof(float));
    ushort_t* hb     = (ushort_t*)alloc((size_t)N_NODES*512*sizeof(ushort_t));
    ushort_t* hbf    = (ushort_t*)alloc((size_t)N_NODES*512*sizeof(ushort_t));
    ushort_t* xbf    = (ushort_t*)alloc((size_t)N_NODES*128*sizeof(ushort_t));
    ushort_t* W0t    = (ushort_t*)alloc((size_t)512*128*sizeof(ushort_t));
    ushort_t* W1t    = (ushort_t*)alloc((size_t)512*512*sizeof(ushort_t));
    float*    h2     = (float*)   alloc((size_t)N_NODES*16*sizeof(float));

    // graph build
    zero_ints<<<(N_NODES+255)/256, 256, 0, stream>>>(wofs, N_NODES);
    count_deg<<<(E_TOT+255)/256, 256, 0, stream>>>(ei, wofs);
    scan_deg<<<1, 1024, 0, stream>>>(wofs, rowptr);
    scatter_edges<<<(E_TOT+255)/256, 256, 0, stream>>>(ei, wofs, csr);

    // bf16 conversions
    cvt_bf16<<<(N_NODES*128+255)/256, 256, 0, stream>>>(x, xbf, N_NODES*128);
    cvt_transpose_bf16<<<(512*128+255)/256, 256, 0, stream>>>(W0, W0t, 128, 512);
    cvt_transpose_bf16<<<(512*512+255)/256, 256, 0, stream>>>(W1, W1t, 512, 512);

    // layer 0
    gemm_bt<128><<<dim3(4, (N_NODES+127)/128), 256, 0, stream>>>(xbf, W0t, hb, N_NODES);
    node_logits<<<(N_NODES*8+255)/256, 256, 0, stream>>>(hb, a_s0, a_d0, als, ald);
    attn_agg<<<N_NODES/4, 256, 0, stream>>>(hb, als, ald, rowptr, csr, b0, hbf);

    // layer 1
    gemm_bt<512><<<dim3(4, (N_NODES+127)/128), 256, 0, stream>>>(hbf, W1t, hb, N_NODES);
    node_logits<<<(N_NODES*8+255)/256, 256, 0, stream>>>(hb, a_s1, a_d1, als, ald);
    attn_agg<<<N_NODES/4, 256, 0, stream>>>(hb, als, ald, rowptr, csr, b1, hbf);

    // layer 2
    gemm2_k<<<(N_NODES*16)/256, 256, 0, stream>>>(hbf, W2, h2);
    node_logits2<<<(N_NODES+255)/256, 256, 0, stream>>>(h2, a_s2, a_d2, als, ald);
    attn_agg2<<<N_NODES/16, 256, 0, stream>>>(h2, als, ald, rowptr, csr, b2, out);
}

// Round 5
// 536.660 us; speedup vs baseline: 2.2403x; 1.2057x over previous
//
#include <hip/hip_runtime.h>

#define N_NODES 50000
#define N_EDGES 400000
#define E_TOT   450000   // + self loops
#define NEG 0.2f
#define NB_SCAN ((N_NODES + 255) / 256)   // 196 blocks

typedef unsigned short ushort_t;
typedef __attribute__((ext_vector_type(8))) short  short8;   // 8 bf16 (4 VGPRs) MFMA A/B frag
typedef __attribute__((ext_vector_type(4))) float  f32x4;    // MFMA C/D frag
typedef __attribute__((ext_vector_type(8))) unsigned short ushort8;

__device__ __forceinline__ ushort_t f2bf(float f){
    union { float f; unsigned u; } v; v.f = f;
    unsigned u = v.u;
    return (ushort_t)((u + 0x7FFFu + ((u >> 16) & 1u)) >> 16);   // RNE
}
__device__ __forceinline__ float bflo(unsigned u){
    union { unsigned u; float f; } v; v.u = u << 16; return v.f;
}
__device__ __forceinline__ float bfhi(unsigned u){
    union { unsigned u; float f; } v; v.u = u & 0xFFFF0000u; return v.f;
}
__device__ __forceinline__ void gload_lds16(const void* g, void* l){
    __builtin_amdgcn_global_load_lds((const __attribute__((address_space(1))) void*)g,
                                     (__attribute__((address_space(3))) void*)l, 16, 0, 0);
}
__device__ __forceinline__ int wave_incl_scan(int v, int lane){
    #pragma unroll
    for(int off = 1; off < 64; off <<= 1){
        int t = __shfl_up(v, off, 64);
        if(lane >= off) v += t;
    }
    return v;
}

// ---------------- graph build ----------------

__global__ void zero_ints(int* p, int n){
    int i = blockIdx.x*256 + threadIdx.x;
    if(i < n) p[i] = 0;
}

__global__ void count_deg(const int* __restrict__ ei, int* __restrict__ deg){
    int e = blockIdx.x*256 + threadIdx.x;
    if(e >= E_TOT) return;
    int dst = (e < N_EDGES) ? ei[N_EDGES + e] : (e - N_EDGES);
    atomicAdd(&deg[dst], 1);
}

// hierarchical scan: block sums -> scan sums -> apply
__global__ void deg_block_sum(const int* __restrict__ deg, int* __restrict__ bsum){
    int i = blockIdx.x*256 + threadIdx.x;
    int lane = threadIdx.x & 63, wave = threadIdx.x >> 6;
    int v = (i < N_NODES) ? deg[i] : 0;
    #pragma unroll
    for(int off = 1; off < 64; off <<= 1) v += __shfl_xor(v, off, 64);
    __shared__ int sw[4];
    if(lane == 0) sw[wave] = v;
    __syncthreads();
    if(threadIdx.x == 0) bsum[blockIdx.x] = sw[0] + sw[1] + sw[2] + sw[3];
}

__global__ void scan_bsum(int* __restrict__ bsum, int* __restrict__ rowptr){
    int lane = threadIdx.x & 63, wave = threadIdx.x >> 6;
    int v = (threadIdx.x < NB_SCAN) ? bsum[threadIdx.x] : 0;
    int incl = wave_incl_scan(v, lane);
    __shared__ int sw[4];
    if(lane == 63) sw[wave] = incl;
    __syncthreads();
    int add = 0;
    for(int w = 0; w < wave; w++) add += sw[w];
    int excl = incl - v + add;
    if(threadIdx.x < NB_SCAN) bsum[threadIdx.x] = excl;
    if(threadIdx.x == 255) rowptr[N_NODES] = excl + v;   // v==0 here, excl==total
}

__global__ void scan_apply(const int* __restrict__ bsum,
                           int* __restrict__ dw, int* __restrict__ rowptr){
    int i = blockIdx.x*256 + threadIdx.x;
    int lane = threadIdx.x & 63, wave = threadIdx.x >> 6;
    int v = (i < N_NODES) ? dw[i] : 0;
    int incl = wave_incl_scan(v, lane);
    __shared__ int sw[4];
    if(lane == 63) sw[wave] = incl;
    __syncthreads();
    int add = bsum[blockIdx.x];
    for(int w = 0; w < wave; w++) add += sw[w];
    int excl = incl - v + add;
    if(i < N_NODES){ rowptr[i] = excl; dw[i] = excl; }
}

__global__ void scatter_edges(const int* __restrict__ ei, int* __restrict__ wofs,
                              int* __restrict__ csr){
    int e = blockIdx.x*256 + threadIdx.x;
    if(e >= E_TOT) return;
    int src, dst;
    if(e < N_EDGES){ src = ei[e]; dst = ei[N_EDGES + e]; }
    else { src = dst = e - N_EDGES; }
    int pos = atomicAdd(&wofs[dst], 1);
    csr[pos] = src;
}

// ---------------- fp32 -> bf16 conversions ----------------

__global__ void cvt_bf16(const float* __restrict__ in, ushort_t* __restrict__ out, int n){
    int i = blockIdx.x*256 + threadIdx.x;
    if(i < n) out[i] = f2bf(in[i]);
}

// Wt[n*K + k] = bf16(W[k*N + n])
__global__ void cvt_transpose_bf16(const float* __restrict__ W, ushort_t* __restrict__ Wt,
                                   int K, int N){
    int t = blockIdx.x*256 + threadIdx.x;
    if(t >= K*N) return;
    int n = t / K, k = t - n*K;
    Wt[t] = f2bf(W[(size_t)k*N + n]);
}

// ---------------- bf16 MFMA GEMM: Cb[M,512](bf16) = A[M,K] @ Bt[512,K]^T ----------------

template<int K>
__global__ __launch_bounds__(256) void gemm_bt(const ushort_t* __restrict__ A,
                                               const ushort_t* __restrict__ Bt,
                                               ushort_t* __restrict__ Cb, int M){
    __shared__ ushort_t As[128*32];
    __shared__ ushort_t Bs[128*32];
    int tid  = threadIdx.x;
    int wave = tid >> 6, lane = tid & 63;
    int wm = wave & 1, wn = wave >> 1;
    int row0 = blockIdx.y * 128;
    int col0 = blockIdx.x * 128;

    f32x4 acc[4][4] = {};

    int lrow = lane >> 2;
    int lchk = (lane & 3) * 8;

    for(int kt = 0; kt < K; kt += 32){
        #pragma unroll
        for(int s = 0; s < 2; s++){
            int seg = wave*2 + s;
            int ar = row0 + seg*16 + lrow;
            ar = ar < M ? ar : M-1;
            gload_lds16(A  + (size_t)ar*K + kt + lchk, As + seg*512);
            int br = col0 + seg*16 + lrow;
            gload_lds16(Bt + (size_t)br*K + kt + lchk, Bs + seg*512);
        }
        __syncthreads();

        short8 a[4], b[4];
        int fm = lane & 15, fq = (lane >> 4) * 8;
        #pragma unroll
        for(int t = 0; t < 4; t++){
            a[t] = *(const short8*)&As[(wm*64 + t*16 + fm)*32 + fq];
            b[t] = *(const short8*)&Bs[(wn*64 + t*16 + fm)*32 + fq];
        }
        #pragma unroll
        for(int i = 0; i < 4; i++)
            #pragma unroll
            for(int j = 0; j < 4; j++)
                acc[i][j] = __builtin_amdgcn_mfma_f32_16x16x32_bf16(a[i], b[j], acc[i][j], 0, 0, 0);
        __syncthreads();
    }

    int cm = (lane >> 4) * 4, cn = lane & 15;
    #pragma unroll
    for(int i = 0; i < 4; i++){
        #pragma unroll
        for(int p = 0; p < 4; p++){
            int r = row0 + wm*64 + i*16 + cm + p;
            if(r < M){
                ushort_t* cp = &Cb[(size_t)r*512 + col0 + wn*64 + cn];
                #pragma unroll
                for(int j = 0; j < 4; j++) cp[j*16] = f2bf(acc[i][j][p]);
            }
        }
    }
}

// ---------------- node attention logits (H=8, C=64), bf16 h ----------------

__global__ void node_logits(const ushort_t* __restrict__ h, const float* __restrict__ a_s,
                            const float* __restrict__ a_d,
                            float* __restrict__ als, float* __restrict__ ald){
    int t = blockIdx.x*256 + threadIdx.x;   // t = n*8 + hd
    if(t >= N_NODES*8) return;
    int hd = t & 7;
    const ushort_t* hp = &h[(size_t)t * 64];
    const float* asp = &a_s[hd*64];
    const float* adp = &a_d[hd*64];
    float s = 0.f, d = 0.f;
    #pragma unroll
    for(int c = 0; c < 64; c += 8){
        uint4 p = *(const uint4*)&hp[c];
        float x0 = bflo(p.x), x1 = bfhi(p.x), x2 = bflo(p.y), x3 = bfhi(p.y);
        float x4 = bflo(p.z), x5 = bfhi(p.z), x6 = bflo(p.w), x7 = bfhi(p.w);
        s += x0*asp[c+0] + x1*asp[c+1] + x2*asp[c+2] + x3*asp[c+3]
           + x4*asp[c+4] + x5*asp[c+5] + x6*asp[c+6] + x7*asp[c+7];
        d += x0*adp[c+0] + x1*adp[c+1] + x2*adp[c+2] + x3*adp[c+3]
           + x4*adp[c+4] + x5*adp[c+5] + x6*adp[c+6] + x7*adp[c+7];
    }
    als[t] = s; ald[t] = d;
}

// ---------------- edge softmax + aggregation (bf16 h gather), bias + ELU, bf16 out ----------------

__global__ __launch_bounds__(256) void attn_agg(const ushort_t* __restrict__ h,
        const float* __restrict__ als, const float* __restrict__ ald,
        const int* __restrict__ rowptr, const int* __restrict__ csr,
        const float* __restrict__ bias, ushort_t* __restrict__ out){
    __shared__ float sm[4][8], sd[4][8];
    int wv = threadIdx.x >> 6, lane = threadIdx.x & 63;
    int n = blockIdx.x*4 + wv;
    int start = rowptr[n], end = rowptr[n+1];

    int hd = lane & 7, e8 = lane >> 3;
    float aldv = ald[n*8 + hd];
    float lmax = -1e30f;
    for(int idx = start + e8; idx < end; idx += 8){
        int src = csr[idx];
        float v = als[src*8 + hd] + aldv;
        v = v > 0.f ? v : NEG*v;
        lmax = fmaxf(lmax, v);
    }
    for(int off = 8; off < 64; off <<= 1) lmax = fmaxf(lmax, __shfl_xor(lmax, off));
    float lsum = 0.f;
    for(int idx = start + e8; idx < end; idx += 8){
        int src = csr[idx];
        float v = als[src*8 + hd] + aldv;
        v = v > 0.f ? v : NEG*v;
        lsum += __expf(v - lmax);
    }
    for(int off = 8; off < 64; off <<= 1) lsum += __shfl_xor(lsum, off);
    if(lane < 8){ sm[wv][hd] = lmax; sd[wv][hd] = 1.f / lsum; }
    __syncthreads();

    int head = lane >> 3;
    float m = sm[wv][head], inv = sd[wv][head];
    float aldn = ald[n*8 + head];
    float acc[8] = {};

    // depth-2 pipeline: prefetch edge idx+1 while accumulating edge idx
    int idx = start;
    int src = csr[idx];
    uint4 p = *(const uint4*)&h[(size_t)src*512 + lane*8];
    float av = als[src*8 + head];
    while(true){
        int nidx = idx + 1;
        bool more = nidx < end;
        int nsrc = 0; uint4 np; float nav = 0.f;
        if(more){
            nsrc = csr[nidx];
            np = *(const uint4*)&h[(size_t)nsrc*512 + lane*8];
            nav = als[nsrc*8 + head];
        }
        float v = av + aldn; v = v > 0.f ? v : NEG*v;
        float alpha = __expf(v - m) * inv;
        acc[0] += alpha*bflo(p.x); acc[1] += alpha*bfhi(p.x);
        acc[2] += alpha*bflo(p.y); acc[3] += alpha*bfhi(p.y);
        acc[4] += alpha*bflo(p.z); acc[5] += alpha*bfhi(p.z);
        acc[6] += alpha*bflo(p.w); acc[7] += alpha*bfhi(p.w);
        if(!more) break;
        idx = nidx; p = np; av = nav;
    }

    ushort8 o;
    #pragma unroll
    for(int j = 0; j < 8; j++){
        float v = acc[j] + bias[lane*8 + j];
        v = v > 0.f ? v : (__expf(v) - 1.f);   // ELU
        o[j] = f2bf(v);
    }
    *(ushort8*)&out[(size_t)n*512 + lane*8] = o;
}

// ---------------- layer 2: GEMM [N,512](bf16) x [512,16](f32) ----------------

__global__ __launch_bounds__(256) void gemm2_k(const ushort_t* __restrict__ A,
                                               const float* __restrict__ W,
                                               float* __restrict__ C){
    __shared__ float Ws[16][513];
    for(int i = threadIdx.x; i < 512*16; i += 256){
        int k = i >> 4, c = i & 15;
        Ws[c][k] = W[i];
    }
    __syncthreads();
    int t = blockIdx.x*256 + threadIdx.x;
    int c = t & 15;
    long row = t >> 4;
    const ushort_t* ap = &A[row*512];
    const float* wp = &Ws[c][0];
    float acc = 0.f;
    for(int k = 0; k < 512; k += 8){
        uint4 p = *(const uint4*)&ap[k];
        acc += bflo(p.x)*wp[k+0] + bfhi(p.x)*wp[k+1]
             + bflo(p.y)*wp[k+2] + bfhi(p.y)*wp[k+3]
             + bflo(p.z)*wp[k+4] + bfhi(p.z)*wp[k+5]
             + bflo(p.w)*wp[k+6] + bfhi(p.w)*wp[k+7];
    }
    C[t] = acc;
}

__global__ void node_logits2(const float* __restrict__ h2, const float* __restrict__ a_s,
                             const float* __restrict__ a_d,
                             float* __restrict__ als, float* __restrict__ ald){
    int n = blockIdx.x*256 + threadIdx.x;
    if(n >= N_NODES) return;
    float s = 0.f, d = 0.f;
    #pragma unroll
    for(int c = 0; c < 16; c++){ float x = h2[n*16+c]; s += x*a_s[c]; d += x*a_d[c]; }
    als[n] = s; ald[n] = d;
}

// final layer agg: 16 lanes per node, 4 nodes per wave, 16 nodes per block
__global__ __launch_bounds__(256) void attn_agg2(const float* __restrict__ h2,
        const float* __restrict__ als, const float* __restrict__ ald,
        const int* __restrict__ rowptr, const int* __restrict__ csr,
        const float* __restrict__ b2, float* __restrict__ out){
    int wv = threadIdx.x >> 6, lane = threadIdx.x & 63;
    int q = lane >> 4, c = lane & 15;
    int n = blockIdx.x*16 + wv*4 + q;
    int start = rowptr[n], end = rowptr[n+1];
    float aldv = ald[n];

    float lmax = -1e30f;
    for(int idx = start + c; idx < end; idx += 16){
        float v = als[csr[idx]] + aldv; v = v > 0.f ? v : NEG*v;
        lmax = fmaxf(lmax, v);
    }
    #pragma unroll
    for(int off = 1; off < 16; off <<= 1) lmax = fmaxf(lmax, __shfl_xor(lmax, off));
    float lsum = 0.f;
    for(int idx = start + c; idx < end; idx += 16){
        float v = als[csr[idx]] + aldv; v = v > 0.f ? v : NEG*v;
        lsum += __expf(v - lmax);
    }
    #pragma unroll
    for(int off = 1; off < 16; off <<= 1) lsum += __shfl_xor(lsum, off);
    float inv = 1.f / lsum;

    float acc = 0.f;
    for(int idx = start; idx < end; idx++){
        int src = csr[idx];
        float v = als[src] + aldv; v = v > 0.f ? v : NEG*v;
        float alpha = __expf(v - lmax) * inv;
        acc += alpha * h2[src*16 + c];
    }
    out[n*16 + c] = acc + b2[c];
}

// ---------------- launch ----------------

extern "C" void kernel_launch(void* const* d_in, const int* in_sizes, int n_in,
                              void* d_out, int out_size, void* d_ws, size_t ws_size,
                              hipStream_t stream) {
    const float* x    = (const float*)d_in[0];
    const int*   ei   = (const int*)  d_in[1];
    const float* W0   = (const float*)d_in[2];
    const float* a_s0 = (const float*)d_in[3];
    const float* a_d0 = (const float*)d_in[4];
    const float* b0   = (const float*)d_in[5];
    const float* W1   = (const float*)d_in[6];
    const float* a_s1 = (const float*)d_in[7];
    const float* a_d1 = (const float*)d_in[8];
    const float* b1   = (const float*)d_in[9];
    const float* W2   = (const float*)d_in[10];
    const float* a_s2 = (const float*)d_in[11];
    const float* a_d2 = (const float*)d_in[12];
    const float* b2   = (const float*)d_in[13];
    float* out = (float*)d_out;

    char* w = (char*)d_ws;
    auto alloc = [&](size_t bytes){ void* p = (void*)w; w += (bytes + 255) & ~(size_t)255; return p; };
    int*      rowptr = (int*)     alloc((N_NODES+1)*sizeof(int));
    int*      wofs   = (int*)     alloc(N_NODES*sizeof(int));
    int*      bsum   = (int*)     alloc(NB_SCAN*sizeof(int));
    int*      csr    = (int*)     alloc(E_TOT*sizeof(int));
    float*    als    = (float*)   alloc((size_t)N_NODES*8*sizeof(float));
    float*    ald    = (float*)   alloc((size_t)N_NODES*8*sizeof(float));
    ushort_t* hb     = (ushort_t*)alloc((size_t)N_NODES*512*sizeof(ushort_t));
    ushort_t* hbf    = (ushort_t*)alloc((size_t)N_NODES*512*sizeof(ushort_t));
    ushort_t* xbf    = (ushort_t*)alloc((size_t)N_NODES*128*sizeof(ushort_t));
    ushort_t* W0t    = (ushort_t*)alloc((size_t)512*128*sizeof(ushort_t));
    ushort_t* W1t    = (ushort_t*)alloc((size_t)512*512*sizeof(ushort_t));
    float*    h2     = (float*)   alloc((size_t)N_NODES*16*sizeof(float));

    // graph build: count -> hierarchical scan -> scatter
    zero_ints<<<(N_NODES+255)/256, 256, 0, stream>>>(wofs, N_NODES);
    count_deg<<<(E_TOT+255)/256, 256, 0, stream>>>(ei, wofs);
    deg_block_sum<<<NB_SCAN, 256, 0, stream>>>(wofs, bsum);
    scan_bsum<<<1, 256, 0, stream>>>(bsum, rowptr);
    scan_apply<<<NB_SCAN, 256, 0, stream>>>(bsum, wofs, rowptr);
    scatter_edges<<<(E_TOT+255)/256, 256, 0, stream>>>(ei, wofs, csr);

    // bf16 conversions
    cvt_bf16<<<(N_NODES*128+255)/256, 256, 0, stream>>>(x, xbf, N_NODES*128);
    cvt_transpose_bf16<<<(512*128+255)/256, 256, 0, stream>>>(W0, W0t, 128, 512);
    cvt_transpose_bf16<<<(512*512+255)/256, 256, 0, stream>>>(W1, W1t, 512, 512);

    // layer 0
    gemm_bt<128><<<dim3(4, (N_NODES+127)/128), 256, 0, stream>>>(xbf, W0t, hb, N_NODES);
    node_logits<<<(N_NODES*8+255)/256, 256, 0, stream>>>(hb, a_s0, a_d0, als, ald);
    attn_agg<<<N_NODES/4, 256, 0, stream>>>(hb, als, ald, rowptr, csr, b0, hbf);

    // layer 1
    gemm_bt<512><<<dim3(4, (N_NODES+127)/128), 256, 0, stream>>>(hbf, W1t, hb, N_NODES);
    node_logits<<<(N_NODES*8+255)/256, 256, 0, stream>>>(hb, a_s1, a_d1, als, ald);
    attn_agg<<<N_NODES/4, 256, 0, stream>>>(hb, als, ald, rowptr, csr, b1, hbf);

    // layer 2
    gemm2_k<<<(N_NODES*16)/256, 256, 0, stream>>>(hbf, W2, h2);
    node_logits2<<<(N_NODES+255)/256, 256, 0, stream>>>(h2, a_s2, a_d2, als, ald);
    attn_agg2<<<N_NODES/16, 256, 0, stream>>>(h2, als, ald, rowptr, csr, b2, out);
}

// Round 6
// 510.600 us; speedup vs baseline: 2.3546x; 1.0510x over previous
//
#include <hip/hip_runtime.h>

#define N_NODES 50000
#define N_EDGES 400000
#define E_TOT   450000   // + self loops
#define NEG 0.2f
#define NB_SCAN ((N_NODES + 255) / 256)   // 196 blocks

typedef unsigned short ushort_t;
typedef __attribute__((ext_vector_type(8))) short  short8;   // 8 bf16 (4 VGPRs) MFMA A/B frag
typedef __attribute__((ext_vector_type(4))) float  f32x4;    // MFMA C/D frag
typedef __attribute__((ext_vector_type(8))) unsigned short ushort8;

__device__ __forceinline__ ushort_t f2bf(float f){
    union { float f; unsigned u; } v; v.f = f;
    unsigned u = v.u;
    return (ushort_t)((u + 0x7FFFu + ((u >> 16) & 1u)) >> 16);   // RNE
}
__device__ __forceinline__ float bflo(unsigned u){
    union { unsigned u; float f; } v; v.u = u << 16; return v.f;
}
__device__ __forceinline__ float bfhi(unsigned u){
    union { unsigned u; float f; } v; v.u = u & 0xFFFF0000u; return v.f;
}
__device__ __forceinline__ void gload_lds16(const void* g, void* l){
    __builtin_amdgcn_global_load_lds((const __attribute__((address_space(1))) void*)g,
                                     (__attribute__((address_space(3))) void*)l, 16, 0, 0);
}
__device__ __forceinline__ int wave_incl_scan(int v, int lane){
    #pragma unroll
    for(int off = 1; off < 64; off <<= 1){
        int t = __shfl_up(v, off, 64);
        if(lane >= off) v += t;
    }
    return v;
}

// ---------------- graph build ----------------

__global__ void zero_ints(int* p, int n){
    int i = blockIdx.x*256 + threadIdx.x;
    if(i < n) p[i] = 0;
}

__global__ void count_deg(const int* __restrict__ ei, int* __restrict__ deg){
    int e = blockIdx.x*256 + threadIdx.x;
    if(e >= E_TOT) return;
    int dst = (e < N_EDGES) ? ei[N_EDGES + e] : (e - N_EDGES);
    atomicAdd(&deg[dst], 1);
}

// hierarchical scan: block sums -> scan sums -> apply
__global__ void deg_block_sum(const int* __restrict__ deg, int* __restrict__ bsum){
    int i = blockIdx.x*256 + threadIdx.x;
    int lane = threadIdx.x & 63, wave = threadIdx.x >> 6;
    int v = (i < N_NODES) ? deg[i] : 0;
    #pragma unroll
    for(int off = 1; off < 64; off <<= 1) v += __shfl_xor(v, off, 64);
    __shared__ int sw[4];
    if(lane == 0) sw[wave] = v;
    __syncthreads();
    if(threadIdx.x == 0) bsum[blockIdx.x] = sw[0] + sw[1] + sw[2] + sw[3];
}

__global__ void scan_bsum(int* __restrict__ bsum, int* __restrict__ rowptr){
    int lane = threadIdx.x & 63, wave = threadIdx.x >> 6;
    int v = (threadIdx.x < NB_SCAN) ? bsum[threadIdx.x] : 0;
    int incl = wave_incl_scan(v, lane);
    __shared__ int sw[4];
    if(lane == 63) sw[wave] = incl;
    __syncthreads();
    int add = 0;
    for(int w = 0; w < wave; w++) add += sw[w];
    int excl = incl - v + add;
    if(threadIdx.x < NB_SCAN) bsum[threadIdx.x] = excl;
    if(threadIdx.x == 255) rowptr[N_NODES] = excl + v;   // v==0 here, excl==total
}

__global__ void scan_apply(const int* __restrict__ bsum,
                           int* __restrict__ dw, int* __restrict__ rowptr){
    int i = blockIdx.x*256 + threadIdx.x;
    int lane = threadIdx.x & 63, wave = threadIdx.x >> 6;
    int v = (i < N_NODES) ? dw[i] : 0;
    int incl = wave_incl_scan(v, lane);
    __shared__ int sw[4];
    if(lane == 63) sw[wave] = incl;
    __syncthreads();
    int add = bsum[blockIdx.x];
    for(int w = 0; w < wave; w++) add += sw[w];
    int excl = incl - v + add;
    if(i < N_NODES){ rowptr[i] = excl; dw[i] = excl; }
}

__global__ void scatter_edges(const int* __restrict__ ei, int* __restrict__ wofs,
                              int* __restrict__ csr){
    int e = blockIdx.x*256 + threadIdx.x;
    if(e >= E_TOT) return;
    int src, dst;
    if(e < N_EDGES){ src = ei[e]; dst = ei[N_EDGES + e]; }
    else { src = dst = e - N_EDGES; }
    int pos = atomicAdd(&wofs[dst], 1);
    csr[pos] = src;
}

// ---------------- fp32 -> bf16 conversions ----------------

__global__ void cvt_bf16(const float* __restrict__ in, ushort_t* __restrict__ out, int n){
    int i = blockIdx.x*256 + threadIdx.x;
    if(i < n) out[i] = f2bf(in[i]);
}

// Wt[n*K + k] = bf16(W[k*N + n])
__global__ void cvt_transpose_bf16(const float* __restrict__ W, ushort_t* __restrict__ Wt,
                                   int K, int N){
    int t = blockIdx.x*256 + threadIdx.x;
    if(t >= K*N) return;
    int n = t / K, k = t - n*K;
    Wt[t] = f2bf(W[(size_t)k*N + n]);
}

// ---------------- bf16 MFMA GEMM: Cb[M,512](bf16) = A[M,K] @ Bt[512,K]^T ----------------

template<int K>
__global__ __launch_bounds__(256) void gemm_bt(const ushort_t* __restrict__ A,
                                               const ushort_t* __restrict__ Bt,
                                               ushort_t* __restrict__ Cb, int M){
    __shared__ ushort_t As[128*32];
    __shared__ ushort_t Bs[128*32];
    int tid  = threadIdx.x;
    int wave = tid >> 6, lane = tid & 63;
    int wm = wave & 1, wn = wave >> 1;
    int row0 = blockIdx.y * 128;
    int col0 = blockIdx.x * 128;

    f32x4 acc[4][4] = {};

    int lrow = lane >> 2;
    int lchk = (lane & 3) * 8;

    for(int kt = 0; kt < K; kt += 32){
        #pragma unroll
        for(int s = 0; s < 2; s++){
            int seg = wave*2 + s;
            int ar = row0 + seg*16 + lrow;
            ar = ar < M ? ar : M-1;
            gload_lds16(A  + (size_t)ar*K + kt + lchk, As + seg*512);
            int br = col0 + seg*16 + lrow;
            gload_lds16(Bt + (size_t)br*K + kt + lchk, Bs + seg*512);
        }
        __syncthreads();

        short8 a[4], b[4];
        int fm = lane & 15, fq = (lane >> 4) * 8;
        #pragma unroll
        for(int t = 0; t < 4; t++){
            a[t] = *(const short8*)&As[(wm*64 + t*16 + fm)*32 + fq];
            b[t] = *(const short8*)&Bs[(wn*64 + t*16 + fm)*32 + fq];
        }
        #pragma unroll
        for(int i = 0; i < 4; i++)
            #pragma unroll
            for(int j = 0; j < 4; j++)
                acc[i][j] = __builtin_amdgcn_mfma_f32_16x16x32_bf16(a[i], b[j], acc[i][j], 0, 0, 0);
        __syncthreads();
    }

    int cm = (lane >> 4) * 4, cn = lane & 15;
    #pragma unroll
    for(int i = 0; i < 4; i++){
        #pragma unroll
        for(int p = 0; p < 4; p++){
            int r = row0 + wm*64 + i*16 + cm + p;
            if(r < M){
                ushort_t* cp = &Cb[(size_t)r*512 + col0 + wn*64 + cn];
                #pragma unroll
                for(int j = 0; j < 4; j++) cp[j*16] = f2bf(acc[i][j][p]);
            }
        }
    }
}

// ---------------- node attention logits (H=8, C=64), bf16 h ----------------

__global__ void node_logits(const ushort_t* __restrict__ h, const float* __restrict__ a_s,
                            const float* __restrict__ a_d,
                            float* __restrict__ als, float* __restrict__ ald){
    int t = blockIdx.x*256 + threadIdx.x;   // t = n*8 + hd
    if(t >= N_NODES*8) return;
    int hd = t & 7;
    const ushort_t* hp = &h[(size_t)t * 64];
    const float* asp = &a_s[hd*64];
    const float* adp = &a_d[hd*64];
    float s = 0.f, d = 0.f;
    #pragma unroll
    for(int c = 0; c < 64; c += 8){
        uint4 p = *(const uint4*)&hp[c];
        float x0 = bflo(p.x), x1 = bfhi(p.x), x2 = bflo(p.y), x3 = bfhi(p.y);
        float x4 = bflo(p.z), x5 = bfhi(p.z), x6 = bflo(p.w), x7 = bfhi(p.w);
        s += x0*asp[c+0] + x1*asp[c+1] + x2*asp[c+2] + x3*asp[c+3]
           + x4*asp[c+4] + x5*asp[c+5] + x6*asp[c+6] + x7*asp[c+7];
        d += x0*adp[c+0] + x1*adp[c+1] + x2*adp[c+2] + x3*adp[c+3]
           + x4*adp[c+4] + x5*adp[c+5] + x6*adp[c+6] + x7*adp[c+7];
    }
    als[t] = s; ald[t] = d;
}

// ---------------- edge softmax + aggregation (bf16 h gather), bias + ELU, bf16 out ----------------
// one wave per node; phase B 4-wide edge unroll for memory-level parallelism.

__global__ __launch_bounds__(256) void attn_agg(const ushort_t* __restrict__ h,
        const float* __restrict__ als, const float* __restrict__ ald,
        const int* __restrict__ rowptr, const int* __restrict__ csr,
        const float* __restrict__ bias, ushort_t* __restrict__ out){
    __shared__ float sm[4][8], sd[4][8];
    int wv = threadIdx.x >> 6, lane = threadIdx.x & 63;
    int n = blockIdx.x*4 + wv;
    int start = rowptr[n], end = rowptr[n+1];

    int hd = lane & 7, e8 = lane >> 3;
    float aldv = ald[n*8 + hd];
    float lmax = -1e30f;
    for(int idx = start + e8; idx < end; idx += 8){
        int src = csr[idx];
        float v = als[src*8 + hd] + aldv;
        v = v > 0.f ? v : NEG*v;
        lmax = fmaxf(lmax, v);
    }
    for(int off = 8; off < 64; off <<= 1) lmax = fmaxf(lmax, __shfl_xor(lmax, off));
    float lsum = 0.f;
    for(int idx = start + e8; idx < end; idx += 8){
        int src = csr[idx];
        float v = als[src*8 + hd] + aldv;
        v = v > 0.f ? v : NEG*v;
        lsum += __expf(v - lmax);
    }
    for(int off = 8; off < 64; off <<= 1) lsum += __shfl_xor(lsum, off);
    if(lane < 8){ sm[wv][hd] = lmax; sd[wv][hd] = 1.f / lsum; }
    __syncthreads();

    int head = lane >> 3;
    float m = sm[wv][head], inv = sd[wv][head];
    float aldn = ald[n*8 + head];
    float acc[8] = {};

    // 4-wide: 4 independent csr->h chains in flight per iteration
    int idx = start;
    for(; idx + 4 <= end; idx += 4){
        int s0 = csr[idx+0], s1 = csr[idx+1], s2 = csr[idx+2], s3 = csr[idx+3];
        uint4 p0 = *(const uint4*)&h[(size_t)s0*512 + lane*8];
        uint4 p1 = *(const uint4*)&h[(size_t)s1*512 + lane*8];
        uint4 p2 = *(const uint4*)&h[(size_t)s2*512 + lane*8];
        uint4 p3 = *(const uint4*)&h[(size_t)s3*512 + lane*8];
        float v0 = als[s0*8 + head] + aldn; v0 = v0 > 0.f ? v0 : NEG*v0;
        float v1 = als[s1*8 + head] + aldn; v1 = v1 > 0.f ? v1 : NEG*v1;
        float v2 = als[s2*8 + head] + aldn; v2 = v2 > 0.f ? v2 : NEG*v2;
        float v3 = als[s3*8 + head] + aldn; v3 = v3 > 0.f ? v3 : NEG*v3;
        float a0 = __expf(v0 - m) * inv;
        float a1 = __expf(v1 - m) * inv;
        float a2 = __expf(v2 - m) * inv;
        float a3 = __expf(v3 - m) * inv;
        acc[0] += a0*bflo(p0.x) + a1*bflo(p1.x) + a2*bflo(p2.x) + a3*bflo(p3.x);
        acc[1] += a0*bfhi(p0.x) + a1*bfhi(p1.x) + a2*bfhi(p2.x) + a3*bfhi(p3.x);
        acc[2] += a0*bflo(p0.y) + a1*bflo(p1.y) + a2*bflo(p2.y) + a3*bflo(p3.y);
        acc[3] += a0*bfhi(p0.y) + a1*bfhi(p1.y) + a2*bfhi(p2.y) + a3*bfhi(p3.y);
        acc[4] += a0*bflo(p0.z) + a1*bflo(p1.z) + a2*bflo(p2.z) + a3*bflo(p3.z);
        acc[5] += a0*bfhi(p0.z) + a1*bfhi(p1.z) + a2*bfhi(p2.z) + a3*bfhi(p3.z);
        acc[6] += a0*bflo(p0.w) + a1*bflo(p1.w) + a2*bflo(p2.w) + a3*bflo(p3.w);
        acc[7] += a0*bfhi(p0.w) + a1*bfhi(p1.w) + a2*bfhi(p2.w) + a3*bfhi(p3.w);
    }
    for(; idx < end; idx++){
        int src = csr[idx];
        float v = als[src*8 + head] + aldn;
        v = v > 0.f ? v : NEG*v;
        float alpha = __expf(v - m) * inv;
        uint4 p = *(const uint4*)&h[(size_t)src*512 + lane*8];
        acc[0] += alpha*bflo(p.x); acc[1] += alpha*bfhi(p.x);
        acc[2] += alpha*bflo(p.y); acc[3] += alpha*bfhi(p.y);
        acc[4] += alpha*bflo(p.z); acc[5] += alpha*bfhi(p.z);
        acc[6] += alpha*bflo(p.w); acc[7] += alpha*bfhi(p.w);
    }

    ushort8 o;
    #pragma unroll
    for(int j = 0; j < 8; j++){
        float v = acc[j] + bias[lane*8 + j];
        v = v > 0.f ? v : (__expf(v) - 1.f);   // ELU
        o[j] = f2bf(v);
    }
    *(ushort8*)&out[(size_t)n*512 + lane*8] = o;
}

// ---------------- layer 2: GEMM [N,512](bf16) x [512,16](f32) ----------------

__global__ __launch_bounds__(256) void gemm2_k(const ushort_t* __restrict__ A,
                                               const float* __restrict__ W,
                                               float* __restrict__ C){
    __shared__ float Ws[16][513];
    for(int i = threadIdx.x; i < 512*16; i += 256){
        int k = i >> 4, c = i & 15;
        Ws[c][k] = W[i];
    }
    __syncthreads();
    int t = blockIdx.x*256 + threadIdx.x;
    int c = t & 15;
    long row = t >> 4;
    const ushort_t* ap = &A[row*512];
    const float* wp = &Ws[c][0];
    float acc = 0.f;
    for(int k = 0; k < 512; k += 8){
        uint4 p = *(const uint4*)&ap[k];
        acc += bflo(p.x)*wp[k+0] + bfhi(p.x)*wp[k+1]
             + bflo(p.y)*wp[k+2] + bfhi(p.y)*wp[k+3]
             + bflo(p.z)*wp[k+4] + bfhi(p.z)*wp[k+5]
             + bflo(p.w)*wp[k+6] + bfhi(p.w)*wp[k+7];
    }
    C[t] = acc;
}

__global__ void node_logits2(const float* __restrict__ h2, const float* __restrict__ a_s,
                             const float* __restrict__ a_d,
                             float* __restrict__ als, float* __restrict__ ald){
    int n = blockIdx.x*256 + threadIdx.x;
    if(n >= N_NODES) return;
    float s = 0.f, d = 0.f;
    #pragma unroll
    for(int c = 0; c < 16; c++){ float x = h2[n*16+c]; s += x*a_s[c]; d += x*a_d[c]; }
    als[n] = s; ald[n] = d;
}

// final layer agg: 16 lanes per node, 4 nodes per wave, 16 nodes per block
__global__ __launch_bounds__(256) void attn_agg2(const float* __restrict__ h2,
        const float* __restrict__ als, const float* __restrict__ ald,
        const int* __restrict__ rowptr, const int* __restrict__ csr,
        const float* __restrict__ b2, float* __restrict__ out){
    int wv = threadIdx.x >> 6, lane = threadIdx.x & 63;
    int q = lane >> 4, c = lane & 15;
    int n = blockIdx.x*16 + wv*4 + q;
    int start = rowptr[n], end = rowptr[n+1];
    float aldv = ald[n];

    float lmax = -1e30f;
    for(int idx = start + c; idx < end; idx += 16){
        float v = als[csr[idx]] + aldv; v = v > 0.f ? v : NEG*v;
        lmax = fmaxf(lmax, v);
    }
    #pragma unroll
    for(int off = 1; off < 16; off <<= 1) lmax = fmaxf(lmax, __shfl_xor(lmax, off));
    float lsum = 0.f;
    for(int idx = start + c; idx < end; idx += 16){
        float v = als[csr[idx]] + aldv; v = v > 0.f ? v : NEG*v;
        lsum += __expf(v - lmax);
    }
    #pragma unroll
    for(int off = 1; off < 16; off <<= 1) lsum += __shfl_xor(lsum, off);
    float inv = 1.f / lsum;

    float acc = 0.f;
    for(int idx = start; idx < end; idx++){
        int src = csr[idx];
        float v = als[src] + aldv; v = v > 0.f ? v : NEG*v;
        float alpha = __expf(v - lmax) * inv;
        acc += alpha * h2[src*16 + c];
    }
    out[n*16 + c] = acc + b2[c];
}

// ---------------- launch ----------------

extern "C" void kernel_launch(void* const* d_in, const int* in_sizes, int n_in,
                              void* d_out, int out_size, void* d_ws, size_t ws_size,
                              hipStream_t stream) {
    const float* x    = (const float*)d_in[0];
    const int*   ei   = (const int*)  d_in[1];
    const float* W0   = (const float*)d_in[2];
    const float* a_s0 = (const float*)d_in[3];
    const float* a_d0 = (const float*)d_in[4];
    const float* b0   = (const float*)d_in[5];
    const float* W1   = (const float*)d_in[6];
    const float* a_s1 = (const float*)d_in[7];
    const float* a_d1 = (const float*)d_in[8];
    const float* b1   = (const float*)d_in[9];
    const float* W2   = (const float*)d_in[10];
    const float* a_s2 = (const float*)d_in[11];
    const float* a_d2 = (const float*)d_in[12];
    const float* b2   = (const float*)d_in[13];
    float* out = (float*)d_out;

    char* w = (char*)d_ws;
    auto alloc = [&](size_t bytes){ void* p = (void*)w; w += (bytes + 255) & ~(size_t)255; return p; };
    int*      rowptr = (int*)     alloc((N_NODES+1)*sizeof(int));
    int*      wofs   = (int*)     alloc(N_NODES*sizeof(int));
    int*      bsum   = (int*)     alloc(NB_SCAN*sizeof(int));
    int*      csr    = (int*)     alloc(E_TOT*sizeof(int));
    float*    als    = (float*)   alloc((size_t)N_NODES*8*sizeof(float));
    float*    ald    = (float*)   alloc((size_t)N_NODES*8*sizeof(float));
    ushort_t* hb     = (ushort_t*)alloc((size_t)N_NODES*512*sizeof(ushort_t));
    ushort_t* hbf    = (ushort_t*)alloc((size_t)N_NODES*512*sizeof(ushort_t));
    ushort_t* xbf    = (ushort_t*)alloc((size_t)N_NODES*128*sizeof(ushort_t));
    ushort_t* W0t    = (ushort_t*)alloc((size_t)512*128*sizeof(ushort_t));
    ushort_t* W1t    = (ushort_t*)alloc((size_t)512*512*sizeof(ushort_t));
    float*    h2     = (float*)   alloc((size_t)N_NODES*16*sizeof(float));

    // graph build: count -> hierarchical scan -> scatter
    zero_ints<<<(N_NODES+255)/256, 256, 0, stream>>>(wofs, N_NODES);
    count_deg<<<(E_TOT+255)/256, 256, 0, stream>>>(ei, wofs);
    deg_block_sum<<<NB_SCAN, 256, 0, stream>>>(wofs, bsum);
    scan_bsum<<<1, 256, 0, stream>>>(bsum, rowptr);
    scan_apply<<<NB_SCAN, 256, 0, stream>>>(bsum, wofs, rowptr);
    scatter_edges<<<(E_TOT+255)/256, 256, 0, stream>>>(ei, wofs, csr);

    // bf16 conversions
    cvt_bf16<<<(N_NODES*128+255)/256, 256, 0, stream>>>(x, xbf, N_NODES*128);
    cvt_transpose_bf16<<<(512*128+255)/256, 256, 0, stream>>>(W0, W0t, 128, 512);
    cvt_transpose_bf16<<<(512*512+255)/256, 256, 0, stream>>>(W1, W1t, 512, 512);

    // layer 0
    gemm_bt<128><<<dim3(4, (N_NODES+127)/128), 256, 0, stream>>>(xbf, W0t, hb, N_NODES);
    node_logits<<<(N_NODES*8+255)/256, 256, 0, stream>>>(hb, a_s0, a_d0, als, ald);
    attn_agg<<<N_NODES/4, 256, 0, stream>>>(hb, als, ald, rowptr, csr, b0, hbf);

    // layer 1
    gemm_bt<512><<<dim3(4, (N_NODES+127)/128), 256, 0, stream>>>(hbf, W1t, hb, N_NODES);
    node_logits<<<(N_NODES*8+255)/256, 256, 0, stream>>>(hb, a_s1, a_d1, als, ald);
    attn_agg<<<N_NODES/4, 256, 0, stream>>>(hb, als, ald, rowptr, csr, b1, hbf);

    // layer 2
    gemm2_k<<<(N_NODES*16)/256, 256, 0, stream>>>(hbf, W2, h2);
    node_logits2<<<(N_NODES+255)/256, 256, 0, stream>>>(h2, a_s2, a_d2, als, ald);
    attn_agg2<<<N_NODES/16, 256, 0, stream>>>(h2, als, ald, rowptr, csr, b2, out);
}

// Round 7
// 462.012 us; speedup vs baseline: 2.6022x; 1.1052x over previous
//
#include <hip/hip_runtime.h>

#define N_NODES 50000
#define N_EDGES 400000
#define E_TOT   450000   // + self loops
#define NEG 0.2f
#define NB_SCAN ((N_NODES + 255) / 256)   // 196 blocks

typedef unsigned short ushort_t;
typedef __attribute__((ext_vector_type(8))) short  short8;   // 8 bf16 (4 VGPRs) MFMA A/B frag
typedef __attribute__((ext_vector_type(4))) float  f32x4;    // MFMA C/D frag
typedef __attribute__((ext_vector_type(8))) unsigned short ushort8;

__device__ __forceinline__ ushort_t f2bf(float f){
    union { float f; unsigned u; } v; v.f = f;
    unsigned u = v.u;
    return (ushort_t)((u + 0x7FFFu + ((u >> 16) & 1u)) >> 16);   // RNE
}
__device__ __forceinline__ float bflo(unsigned u){
    union { unsigned u; float f; } v; v.u = u << 16; return v.f;
}
__device__ __forceinline__ float bfhi(unsigned u){
    union { unsigned u; float f; } v; v.u = u & 0xFFFF0000u; return v.f;
}
__device__ __forceinline__ void gload_lds16(const void* g, void* l){
    __builtin_amdgcn_global_load_lds((const __attribute__((address_space(1))) void*)g,
                                     (__attribute__((address_space(3))) void*)l, 16, 0, 0);
}
__device__ __forceinline__ int wave_incl_scan(int v, int lane){
    #pragma unroll
    for(int off = 1; off < 64; off <<= 1){
        int t = __shfl_up(v, off, 64);
        if(lane >= off) v += t;
    }
    return v;
}

// ---------------- graph build ----------------

__global__ void zero_ints(int* p, int n){
    int i = blockIdx.x*256 + threadIdx.x;
    if(i < n) p[i] = 0;
}

__global__ void count_deg(const int* __restrict__ ei, int* __restrict__ deg){
    int e = blockIdx.x*256 + threadIdx.x;
    if(e >= E_TOT) return;
    int dst = (e < N_EDGES) ? ei[N_EDGES + e] : (e - N_EDGES);
    atomicAdd(&deg[dst], 1);
}

// hierarchical scan: block sums -> scan sums -> apply
__global__ void deg_block_sum(const int* __restrict__ deg, int* __restrict__ bsum){
    int i = blockIdx.x*256 + threadIdx.x;
    int lane = threadIdx.x & 63, wave = threadIdx.x >> 6;
    int v = (i < N_NODES) ? deg[i] : 0;
    #pragma unroll
    for(int off = 1; off < 64; off <<= 1) v += __shfl_xor(v, off, 64);
    __shared__ int sw[4];
    if(lane == 0) sw[wave] = v;
    __syncthreads();
    if(threadIdx.x == 0) bsum[blockIdx.x] = sw[0] + sw[1] + sw[2] + sw[3];
}

__global__ void scan_bsum(int* __restrict__ bsum, int* __restrict__ rowptr){
    int lane = threadIdx.x & 63, wave = threadIdx.x >> 6;
    int v = (threadIdx.x < NB_SCAN) ? bsum[threadIdx.x] : 0;
    int incl = wave_incl_scan(v, lane);
    __shared__ int sw[4];
    if(lane == 63) sw[wave] = incl;
    __syncthreads();
    int add = 0;
    for(int w = 0; w < wave; w++) add += sw[w];
    int excl = incl - v + add;
    if(threadIdx.x < NB_SCAN) bsum[threadIdx.x] = excl;
    if(threadIdx.x == 255) rowptr[N_NODES] = excl + v;
}

__global__ void scan_apply(const int* __restrict__ bsum,
                           int* __restrict__ dw, int* __restrict__ rowptr){
    int i = blockIdx.x*256 + threadIdx.x;
    int lane = threadIdx.x & 63, wave = threadIdx.x >> 6;
    int v = (i < N_NODES) ? dw[i] : 0;
    int incl = wave_incl_scan(v, lane);
    __shared__ int sw[4];
    if(lane == 63) sw[wave] = incl;
    __syncthreads();
    int add = bsum[blockIdx.x];
    for(int w = 0; w < wave; w++) add += sw[w];
    int excl = incl - v + add;
    if(i < N_NODES){ rowptr[i] = excl; dw[i] = excl; }
}

__global__ void scatter_edges(const int* __restrict__ ei, int* __restrict__ wofs,
                              int* __restrict__ csr){
    int e = blockIdx.x*256 + threadIdx.x;
    if(e >= E_TOT) return;
    int src, dst;
    if(e < N_EDGES){ src = ei[e]; dst = ei[N_EDGES + e]; }
    else { src = dst = e - N_EDGES; }
    int pos = atomicAdd(&wofs[dst], 1);
    csr[pos] = src;
}

// ---------------- fused fp32 -> bf16 conversions (x, W0^T, W1^T) ----------------

__global__ void cvt_all(const float* __restrict__ x, const float* __restrict__ W0,
                        const float* __restrict__ W1,
                        ushort_t* __restrict__ xbf, ushort_t* __restrict__ W0t,
                        ushort_t* __restrict__ W1t){
    int i = blockIdx.x*256 + threadIdx.x;
    if(i < N_NODES*128) xbf[i] = f2bf(x[i]);
    if(i < 512*128){ int n = i >> 7, k = i & 127; W0t[i] = f2bf(W0[(size_t)k*512 + n]); }
    if(i < 512*512){ int n = i >> 9, k = i & 511; W1t[i] = f2bf(W1[(size_t)k*512 + n]); }
}

// ---------------- bf16 MFMA GEMM + fused attention logits ----------------
// Cb[M,512](bf16) = A[M,K] @ Bt[512,K]^T ; als/ald[M,8] = Cb . a_s/a_d per head.
// Block (bx,by) holds ALL 64 cols of heads 2bx,2bx+1 for its 128 rows -> logits
// computed by 16-lane cross reduction, no atomics.

template<int K>
__global__ __launch_bounds__(256) void gemm_bt(const ushort_t* __restrict__ A,
                                               const ushort_t* __restrict__ Bt,
                                               ushort_t* __restrict__ Cb,
                                               const float* __restrict__ a_s,
                                               const float* __restrict__ a_d,
                                               float* __restrict__ als,
                                               float* __restrict__ ald, int M){
    __shared__ ushort_t As[128*32];
    __shared__ ushort_t Bs[128*32];
    int tid  = threadIdx.x;
    int wave = tid >> 6, lane = tid & 63;
    int wm = wave & 1, wn = wave >> 1;
    int row0 = blockIdx.y * 128;
    int col0 = blockIdx.x * 128;

    f32x4 acc[4][4] = {};

    int lrow = lane >> 2;
    int lchk = (lane & 3) * 8;

    for(int kt = 0; kt < K; kt += 32){
        #pragma unroll
        for(int s = 0; s < 2; s++){
            int seg = wave*2 + s;
            int ar = row0 + seg*16 + lrow;
            ar = ar < M ? ar : M-1;
            gload_lds16(A  + (size_t)ar*K + kt + lchk, As + seg*512);
            int br = col0 + seg*16 + lrow;
            gload_lds16(Bt + (size_t)br*K + kt + lchk, Bs + seg*512);
        }
        __syncthreads();

        short8 a[4], b[4];
        int fm = lane & 15, fq = (lane >> 4) * 8;
        #pragma unroll
        for(int t = 0; t < 4; t++){
            a[t] = *(const short8*)&As[(wm*64 + t*16 + fm)*32 + fq];
            b[t] = *(const short8*)&Bs[(wn*64 + t*16 + fm)*32 + fq];
        }
        #pragma unroll
        for(int i = 0; i < 4; i++)
            #pragma unroll
            for(int j = 0; j < 4; j++)
                acc[i][j] = __builtin_amdgcn_mfma_f32_16x16x32_bf16(a[i], b[j], acc[i][j], 0, 0, 0);
        __syncthreads();
    }

    // epilogue: store bf16 C + fused logits
    int cm = (lane >> 4) * 4, cn = lane & 15;
    int head = (col0 + wn*64) >> 6;           // uniform per wave
    float as_[4], ad_[4];
    #pragma unroll
    for(int j = 0; j < 4; j++){
        int c = head*64 + cn + j*16;
        as_[j] = a_s[c]; ad_[j] = a_d[c];
    }
    #pragma unroll
    for(int i = 0; i < 4; i++){
        #pragma unroll
        for(int p = 0; p < 4; p++){
            int r = row0 + wm*64 + i*16 + cm + p;   // uniform across 16-lane group
            float ps = 0.f, pd = 0.f;
            if(r < M){
                ushort_t* cp = &Cb[(size_t)r*512 + col0 + wn*64 + cn];
                #pragma unroll
                for(int j = 0; j < 4; j++){
                    float v = acc[i][j][p];
                    cp[j*16] = f2bf(v);
                    ps += v*as_[j]; pd += v*ad_[j];
                }
            }
            #pragma unroll
            for(int off = 1; off < 16; off <<= 1){
                ps += __shfl_xor(ps, off);
                pd += __shfl_xor(pd, off);
            }
            if(cn == 0 && r < M){ als[r*8 + head] = ps; ald[r*8 + head] = pd; }
        }
    }
}

// ---------------- edge softmax + aggregation (bf16 h gather), bias + ELU, bf16 out ----------------
// one wave per node; phase B masked 4-wide (no serial remainder).

__global__ __launch_bounds__(256) void attn_agg(const ushort_t* __restrict__ h,
        const float* __restrict__ als, const float* __restrict__ ald,
        const int* __restrict__ rowptr, const int* __restrict__ csr,
        const float* __restrict__ bias, ushort_t* __restrict__ out){
    __shared__ float sm[4][8], sd[4][8];
    int wv = threadIdx.x >> 6, lane = threadIdx.x & 63;
    int n = blockIdx.x*4 + wv;
    int start = rowptr[n], end = rowptr[n+1];

    int hd = lane & 7, e8 = lane >> 3;
    float aldv = ald[n*8 + hd];
    float lmax = -1e30f;
    for(int idx = start + e8; idx < end; idx += 8){
        int src = csr[idx];
        float v = als[src*8 + hd] + aldv;
        v = v > 0.f ? v : NEG*v;
        lmax = fmaxf(lmax, v);
    }
    for(int off = 8; off < 64; off <<= 1) lmax = fmaxf(lmax, __shfl_xor(lmax, off));
    float lsum = 0.f;
    for(int idx = start + e8; idx < end; idx += 8){
        int src = csr[idx];
        float v = als[src*8 + hd] + aldv;
        v = v > 0.f ? v : NEG*v;
        lsum += __expf(v - lmax);
    }
    for(int off = 8; off < 64; off <<= 1) lsum += __shfl_xor(lsum, off);
    if(lane < 8){ sm[wv][hd] = lmax; sd[wv][hd] = 1.f / lsum; }
    __syncthreads();

    int head = lane >> 3;
    float m = sm[wv][head], inv = sd[wv][head];
    float aldn = ald[n*8 + head];
    float acc[8] = {};

    int last = end - 1;
    for(int idx = start; idx < end; idx += 4){
        int j1 = idx+1, j2 = idx+2, j3 = idx+3;
        int s0 = csr[idx];
        int s1 = csr[j1 <= last ? j1 : last];
        int s2 = csr[j2 <= last ? j2 : last];
        int s3 = csr[j3 <= last ? j3 : last];
        uint4 p0 = *(const uint4*)&h[(size_t)s0*512 + lane*8];
        uint4 p1 = *(const uint4*)&h[(size_t)s1*512 + lane*8];
        uint4 p2 = *(const uint4*)&h[(size_t)s2*512 + lane*8];
        uint4 p3 = *(const uint4*)&h[(size_t)s3*512 + lane*8];
        float v0 = als[s0*8 + head] + aldn; v0 = v0 > 0.f ? v0 : NEG*v0;
        float v1 = als[s1*8 + head] + aldn; v1 = v1 > 0.f ? v1 : NEG*v1;
        float v2 = als[s2*8 + head] + aldn; v2 = v2 > 0.f ? v2 : NEG*v2;
        float v3 = als[s3*8 + head] + aldn; v3 = v3 > 0.f ? v3 : NEG*v3;
        float e0 = __expf(v0 - m);
        float e1 = (j1 < end) ? __expf(v1 - m) : 0.f;
        float e2 = (j2 < end) ? __expf(v2 - m) : 0.f;
        float e3 = (j3 < end) ? __expf(v3 - m) : 0.f;
        acc[0] += e0*bflo(p0.x) + e1*bflo(p1.x) + e2*bflo(p2.x) + e3*bflo(p3.x);
        acc[1] += e0*bfhi(p0.x) + e1*bfhi(p1.x) + e2*bfhi(p2.x) + e3*bfhi(p3.x);
        acc[2] += e0*bflo(p0.y) + e1*bflo(p1.y) + e2*bflo(p2.y) + e3*bflo(p3.y);
        acc[3] += e0*bfhi(p0.y) + e1*bfhi(p1.y) + e2*bfhi(p2.y) + e3*bfhi(p3.y);
        acc[4] += e0*bflo(p0.z) + e1*bflo(p1.z) + e2*bflo(p2.z) + e3*bflo(p3.z);
        acc[5] += e0*bfhi(p0.z) + e1*bfhi(p1.z) + e2*bfhi(p2.z) + e3*bfhi(p3.z);
        acc[6] += e0*bflo(p0.w) + e1*bflo(p1.w) + e2*bflo(p2.w) + e3*bflo(p3.w);
        acc[7] += e0*bfhi(p0.w) + e1*bfhi(p1.w) + e2*bfhi(p2.w) + e3*bfhi(p3.w);
    }

    ushort8 o;
    #pragma unroll
    for(int j = 0; j < 8; j++){
        float v = acc[j]*inv + bias[lane*8 + j];
        v = v > 0.f ? v : (__expf(v) - 1.f);   // ELU
        o[j] = f2bf(v);
    }
    *(ushort8*)&out[(size_t)n*512 + lane*8] = o;
}

// ---------------- layer 2: GEMM [N,512](bf16) x [512,16](f32) + fused logits2 ----------------

__global__ __launch_bounds__(256) void gemm2_k(const ushort_t* __restrict__ A,
                                               const float* __restrict__ W,
                                               const float* __restrict__ a_s2,
                                               const float* __restrict__ a_d2,
                                               float* __restrict__ C,
                                               float* __restrict__ als,
                                               float* __restrict__ ald){
    __shared__ float Ws[16][513];
    for(int i = threadIdx.x; i < 512*16; i += 256){
        int k = i >> 4, c = i & 15;
        Ws[c][k] = W[i];
    }
    __syncthreads();
    int t = blockIdx.x*256 + threadIdx.x;
    int c = t & 15;
    long row = t >> 4;
    const ushort_t* ap = &A[row*512];
    const float* wp = &Ws[c][0];
    float acc = 0.f;
    for(int k = 0; k < 512; k += 8){
        uint4 p = *(const uint4*)&ap[k];
        acc += bflo(p.x)*wp[k+0] + bfhi(p.x)*wp[k+1]
             + bflo(p.y)*wp[k+2] + bfhi(p.y)*wp[k+3]
             + bflo(p.z)*wp[k+4] + bfhi(p.z)*wp[k+5]
             + bflo(p.w)*wp[k+6] + bfhi(p.w)*wp[k+7];
    }
    C[t] = acc;
    // fused logits2: threads c=0..15 of the same row sit in one 16-lane group
    float ps = acc * a_s2[c], pd = acc * a_d2[c];
    #pragma unroll
    for(int off = 1; off < 16; off <<= 1){
        ps += __shfl_xor(ps, off);
        pd += __shfl_xor(pd, off);
    }
    if(c == 0){ als[row] = ps; ald[row] = pd; }
}

// final layer agg: 16 lanes per node, 4 nodes per wave, 16 nodes per block
__global__ __launch_bounds__(256) void attn_agg2(const float* __restrict__ h2,
        const float* __restrict__ als, const float* __restrict__ ald,
        const int* __restrict__ rowptr, const int* __restrict__ csr,
        const float* __restrict__ b2, float* __restrict__ out){
    int wv = threadIdx.x >> 6, lane = threadIdx.x & 63;
    int q = lane >> 4, c = lane & 15;
    int n = blockIdx.x*16 + wv*4 + q;
    int start = rowptr[n], end = rowptr[n+1];
    float aldv = ald[n];

    float lmax = -1e30f;
    for(int idx = start + c; idx < end; idx += 16){
        float v = als[csr[idx]] + aldv; v = v > 0.f ? v : NEG*v;
        lmax = fmaxf(lmax, v);
    }
    #pragma unroll
    for(int off = 1; off < 16; off <<= 1) lmax = fmaxf(lmax, __shfl_xor(lmax, off));
    float lsum = 0.f;
    for(int idx = start + c; idx < end; idx += 16){
        float v = als[csr[idx]] + aldv; v = v > 0.f ? v : NEG*v;
        lsum += __expf(v - lmax);
    }
    #pragma unroll
    for(int off = 1; off < 16; off <<= 1) lsum += __shfl_xor(lsum, off);
    float inv = 1.f / lsum;

    float acc = 0.f;
    for(int idx = start; idx < end; idx++){
        int src = csr[idx];
        float v = als[src] + aldv; v = v > 0.f ? v : NEG*v;
        float alpha = __expf(v - lmax) * inv;
        acc += alpha * h2[src*16 + c];
    }
    out[n*16 + c] = acc + b2[c];
}

// ---------------- launch ----------------

extern "C" void kernel_launch(void* const* d_in, const int* in_sizes, int n_in,
                              void* d_out, int out_size, void* d_ws, size_t ws_size,
                              hipStream_t stream) {
    const float* x    = (const float*)d_in[0];
    const int*   ei   = (const int*)  d_in[1];
    const float* W0   = (const float*)d_in[2];
    const float* a_s0 = (const float*)d_in[3];
    const float* a_d0 = (const float*)d_in[4];
    const float* b0   = (const float*)d_in[5];
    const float* W1   = (const float*)d_in[6];
    const float* a_s1 = (const float*)d_in[7];
    const float* a_d1 = (const float*)d_in[8];
    const float* b1   = (const float*)d_in[9];
    const float* W2   = (const float*)d_in[10];
    const float* a_s2 = (const float*)d_in[11];
    const float* a_d2 = (const float*)d_in[12];
    const float* b2   = (const float*)d_in[13];
    float* out = (float*)d_out;

    char* w = (char*)d_ws;
    auto alloc = [&](size_t bytes){ void* p = (void*)w; w += (bytes + 255) & ~(size_t)255; return p; };
    int*      rowptr = (int*)     alloc((N_NODES+1)*sizeof(int));
    int*      wofs   = (int*)     alloc(N_NODES*sizeof(int));
    int*      bsum   = (int*)     alloc(NB_SCAN*sizeof(int));
    int*      csr    = (int*)     alloc(E_TOT*sizeof(int));
    float*    als    = (float*)   alloc((size_t)N_NODES*8*sizeof(float));
    float*    ald    = (float*)   alloc((size_t)N_NODES*8*sizeof(float));
    ushort_t* hb     = (ushort_t*)alloc((size_t)N_NODES*512*sizeof(ushort_t));
    ushort_t* hbf    = (ushort_t*)alloc((size_t)N_NODES*512*sizeof(ushort_t));
    ushort_t* xbf    = (ushort_t*)alloc((size_t)N_NODES*128*sizeof(ushort_t));
    ushort_t* W0t    = (ushort_t*)alloc((size_t)512*128*sizeof(ushort_t));
    ushort_t* W1t    = (ushort_t*)alloc((size_t)512*512*sizeof(ushort_t));
    float*    h2     = (float*)   alloc((size_t)N_NODES*16*sizeof(float));

    // graph build: count -> hierarchical scan -> scatter
    zero_ints<<<(N_NODES+255)/256, 256, 0, stream>>>(wofs, N_NODES);
    count_deg<<<(E_TOT+255)/256, 256, 0, stream>>>(ei, wofs);
    deg_block_sum<<<NB_SCAN, 256, 0, stream>>>(wofs, bsum);
    scan_bsum<<<1, 256, 0, stream>>>(bsum, rowptr);
    scan_apply<<<NB_SCAN, 256, 0, stream>>>(bsum, wofs, rowptr);
    scatter_edges<<<(E_TOT+255)/256, 256, 0, stream>>>(ei, wofs, csr);

    // fused bf16 conversions
    cvt_all<<<(N_NODES*128+255)/256, 256, 0, stream>>>(x, W0, W1, xbf, W0t, W1t);

    // layer 0 (logits fused into gemm epilogue)
    gemm_bt<128><<<dim3(4, (N_NODES+127)/128), 256, 0, stream>>>(xbf, W0t, hb, a_s0, a_d0, als, ald, N_NODES);
    attn_agg<<<N_NODES/4, 256, 0, stream>>>(hb, als, ald, rowptr, csr, b0, hbf);

    // layer 1
    gemm_bt<512><<<dim3(4, (N_NODES+127)/128), 256, 0, stream>>>(hbf, W1t, hb, a_s1, a_d1, als, ald, N_NODES);
    attn_agg<<<N_NODES/4, 256, 0, stream>>>(hb, als, ald, rowptr, csr, b1, hbf);

    // layer 2 (logits2 fused)
    gemm2_k<<<(N_NODES*16)/256, 256, 0, stream>>>(hbf, W2, a_s2, a_d2, h2, als, ald);
    attn_agg2<<<N_NODES/16, 256, 0, stream>>>(h2, als, ald, rowptr, csr, b2, out);
}